// Round 1
// baseline (2415.585 us; speedup 1.0000x reference)
//
#include <hip/hip_runtime.h>
#include <hip/hip_bf16.h>
#include <math.h>

#define N_NODES 50000
#define N_EDGES 600000
#define N_PATHS 3
#define DIM 128          // IN_DIM == OUT_DIM == SEM_HID == 128

// ---------------- degree kernel ----------------
__global__ void deg_kernel(const int* __restrict__ esrc, const int* __restrict__ edst,
                           float* __restrict__ deg_out, float* __restrict__ deg_in) {
    int i = blockIdx.x * blockDim.x + threadIdx.x;
    const int total = N_PATHS * N_EDGES;
    if (i < total) {
        int p = i / N_EDGES;
        atomicAdd(&deg_out[p * N_NODES + esrc[i]], 1.0f);
        atomicAdd(&deg_in [p * N_NODES + edst[i]], 1.0f);
    }
}

// ---------------- per-path matmul: x = (h * rsqrt(max(deg_out,1))) @ W ----------------
#define MM_ROWS 64
__global__ __launch_bounds__(128) void gc_matmul(const float* __restrict__ h,
                                                 const float* __restrict__ W,     // [128][128]
                                                 const float* __restrict__ degp,  // [N]
                                                 float* __restrict__ x) {         // [N][128]
    __shared__ float Ws[DIM * DIM];
    __shared__ float hrow[DIM];
    int tid = threadIdx.x;  // 0..127  (column)
    for (int k = 0; k < DIM; ++k) Ws[k * DIM + tid] = W[k * DIM + tid];
    __syncthreads();
    int row0 = blockIdx.x * MM_ROWS;
    for (int r = 0; r < MM_ROWS; ++r) {
        int n = row0 + r;
        if (n >= N_NODES) break;                      // uniform across block
        float scale = rsqrtf(fmaxf(degp[n], 1.0f));
        hrow[tid] = h[(size_t)n * DIM + tid] * scale;
        __syncthreads();
        float acc = 0.0f;
#pragma unroll 8
        for (int k = 0; k < DIM; ++k) acc = fmaf(hrow[k], Ws[k * DIM + tid], acc);
        x[(size_t)n * DIM + tid] = acc;
        __syncthreads();                              // hrow reused next iter
    }
}

// ---------------- per-path scatter: z[dst] += x[src] ----------------
__global__ __launch_bounds__(256) void scatter_kernel(const int* __restrict__ src,
                                                      const int* __restrict__ dst,
                                                      const float* __restrict__ x,
                                                      float* __restrict__ zp) {
    int e = blockIdx.x * 2 + (threadIdx.x >> 7);
    int d = threadIdx.x & 127;
    if (e < N_EDGES) {
        int s = src[e];
        int t = dst[e];
        atomicAdd(&zp[(size_t)t * DIM + d], x[(size_t)s * DIM + d]);
    }
}

// ---------------- finalize: z = z * rsqrt(max(deg_in,1)) + b ----------------
__global__ void finalize_kernel(float* __restrict__ z, const float* __restrict__ deg_in,
                                const float* __restrict__ b_gc) {
    int i = blockIdx.x * blockDim.x + threadIdx.x;   // over P*N*D = 19.2M
    const int total = N_PATHS * N_NODES * DIM;
    if (i < total) {
        int d  = i & (DIM - 1);
        int pn = i >> 7;              // p*N + n
        int p  = pn / N_NODES;
        z[i] = z[i] * rsqrtf(fmaxf(deg_in[pn], 1.0f)) + b_gc[p * DIM + d];
    }
}

// ---------------- semantic score: sum over rows of tanh(z@w1+b1)@w2, per path ----------------
#define SROWS 32
__global__ __launch_bounds__(128) void score_kernel(const float* __restrict__ z,
                                                    const float* __restrict__ w1,
                                                    const float* __restrict__ b1,
                                                    const float* __restrict__ w2,
                                                    float* __restrict__ score) {  // [3] sums
    __shared__ float w1s[DIM * DIM];
    __shared__ float zrow[DIM];
    __shared__ float wred[2];
    int tid = threadIdx.x;   // 0..127 (output col j)
    for (int k = 0; k < DIM; ++k) w1s[k * DIM + tid] = w1[k * DIM + tid];
    float bj  = b1[tid];
    float w2j = w2[tid];
    __syncthreads();
    float pacc[N_PATHS] = {0.f, 0.f, 0.f};
    int row0 = blockIdx.x * SROWS;
    for (int r = 0; r < SROWS; ++r) {
        int row = row0 + r;                         // p*N + n
        if (row >= N_PATHS * N_NODES) break;        // uniform
        zrow[tid] = z[(size_t)row * DIM + tid];
        __syncthreads();
        float acc = bj;
#pragma unroll 8
        for (int k = 0; k < DIM; ++k) acc = fmaf(zrow[k], w1s[k * DIM + tid], acc);
        float s = tanhf(acc) * w2j;
        // reduce across 128 threads (2 waves)
#pragma unroll
        for (int off = 32; off > 0; off >>= 1) s += __shfl_xor(s, off, 64);
        int lane = tid & 63, wid = tid >> 6;
        if (lane == 0) wred[wid] = s;
        __syncthreads();
        if (tid == 0) pacc[row / N_NODES] += wred[0] + wred[1];
        __syncthreads();                            // before zrow/wred overwrite
    }
    if (tid == 0) {
#pragma unroll
        for (int p = 0; p < N_PATHS; ++p) atomicAdd(&score[p], pacc[p]);
    }
}

// ---------------- beta = softmax(score / N) ----------------
__global__ void beta_kernel(const float* __restrict__ score, float* __restrict__ beta) {
    if (threadIdx.x == 0 && blockIdx.x == 0) {
        float a = score[0] / (float)N_NODES;
        float b = score[1] / (float)N_NODES;
        float c = score[2] / (float)N_NODES;
        float m = fmaxf(a, fmaxf(b, c));
        float e0 = expf(a - m), e1 = expf(b - m), e2 = expf(c - m);
        float s = e0 + e1 + e2;
        beta[0] = e0 / s; beta[1] = e1 / s; beta[2] = e2 / s;
    }
}

// ---------------- out = sum_p beta[p] * z[p] ----------------
__global__ void out_kernel(const float* __restrict__ z, const float* __restrict__ beta,
                           float* __restrict__ out) {
    int i = blockIdx.x * blockDim.x + threadIdx.x;  // over N*D
    const int nd = N_NODES * DIM;
    if (i < nd) {
        out[i] = beta[0] * z[i] + beta[1] * z[nd + i] + beta[2] * z[2 * (size_t)nd + i];
    }
}

extern "C" void kernel_launch(void* const* d_in, const int* in_sizes, int n_in,
                              void* d_out, int out_size, void* d_ws, size_t ws_size,
                              hipStream_t stream) {
    const float* h    = (const float*)d_in[0];   // [N,128]
    const float* W_gc = (const float*)d_in[1];   // [3,128,128]
    const float* b_gc = (const float*)d_in[2];   // [3,128]
    const float* w1   = (const float*)d_in[3];   // [128,128]
    const float* b1   = (const float*)d_in[4];   // [128]
    const float* w2   = (const float*)d_in[5];   // [128]
    const int* esrc   = (const int*)d_in[6];     // [3,E]
    const int* edst   = (const int*)d_in[7];     // [3,E]
    float* out        = (float*)d_out;

    // workspace layout (floats)
    float* ws       = (float*)d_ws;
    float* deg_out  = ws;                                  // P*N
    float* deg_in   = deg_out + N_PATHS * N_NODES;         // P*N
    float* score    = deg_in + N_PATHS * N_NODES;          // 3
    float* beta     = score + N_PATHS;                     // 3
    const size_t Z_OFF = 300032;                           // aligned past deg/score/beta
    float* z        = ws + Z_OFF;                          // P*N*D
    float* x        = z + (size_t)N_PATHS * N_NODES * DIM; // N*D

    // zero: deg_out, deg_in, score (+beta pad) and z — one contiguous memset
    size_t zero_bytes = (Z_OFF + (size_t)N_PATHS * N_NODES * DIM) * sizeof(float);
    hipMemsetAsync(d_ws, 0, zero_bytes, stream);

    // degrees
    {
        int total = N_PATHS * N_EDGES;
        deg_kernel<<<(total + 255) / 256, 256, 0, stream>>>(esrc, edst, deg_out, deg_in);
    }

    // per-path: matmul then scatter (x reused; stream order serializes)
    for (int p = 0; p < N_PATHS; ++p) {
        gc_matmul<<<(N_NODES + MM_ROWS - 1) / MM_ROWS, 128, 0, stream>>>(
            h, W_gc + (size_t)p * DIM * DIM, deg_out + (size_t)p * N_NODES, x);
        scatter_kernel<<<(N_EDGES + 1) / 2, 256, 0, stream>>>(
            esrc + (size_t)p * N_EDGES, edst + (size_t)p * N_EDGES, x,
            z + (size_t)p * N_NODES * DIM);
    }

    // finalize z
    {
        int total = N_PATHS * N_NODES * DIM;
        finalize_kernel<<<(total + 255) / 256, 256, 0, stream>>>(z, deg_in, b_gc);
    }

    // semantic attention scores
    {
        int rows = N_PATHS * N_NODES;
        score_kernel<<<(rows + SROWS - 1) / SROWS, 128, 0, stream>>>(z, w1, b1, w2, score);
    }

    beta_kernel<<<1, 64, 0, stream>>>(score, beta);

    {
        int nd = N_NODES * DIM;
        out_kernel<<<(nd + 255) / 256, 256, 0, stream>>>(z, beta, out);
    }
}

// Round 2
// 1284.223 us; speedup vs baseline: 1.8810x; 1.8810x over previous
//
#include <hip/hip_runtime.h>
#include <hip/hip_bf16.h>
#include <math.h>

#define N_NODES 50000
#define N_EDGES 600000
#define N_PATHS 3
#define DIM 128          // IN_DIM == OUT_DIM == SEM_HID == 128
#define BK 16            // K-chunk staged in LDS

__device__ __forceinline__ float tanh_fast(float x) {
    // 1 - 2/(e^{2x}+1): monotone, saturates to +-1 without NaN at large |x|
    return 1.0f - 2.0f / (__expf(2.0f * x) + 1.0f);
}

// ---------------- degree kernel ----------------
__global__ void deg_kernel(const int* __restrict__ esrc, const int* __restrict__ edst,
                           float* __restrict__ deg_out, float* __restrict__ deg_in) {
    int i = blockIdx.x * blockDim.x + threadIdx.x;
    const int total = N_PATHS * N_EDGES;
    if (i < total) {
        int p = i / N_EDGES;
        atomicAdd(&deg_out[p * N_NODES + esrc[i]], 1.0f);
        atomicAdd(&deg_in [p * N_NODES + edst[i]], 1.0f);
    }
}

// ---------------- tiled SGEMM: x = (h * rsqrt(max(deg_out,1))) @ W ----------------
// block: 256 threads, 128x128 output tile, 8x8 per thread. B (W) fully in LDS.
__global__ __launch_bounds__(256, 2) void gc_matmul(const float* __restrict__ h,
                                                    const float* __restrict__ W,     // [128][128]
                                                    const float* __restrict__ degp,  // [N]
                                                    float* __restrict__ x) {         // [N][128]
    __shared__ float Ws[DIM * DIM];     // 64 KB, [k][j]
    __shared__ float As[BK * DIM];      // 8 KB,  [k][r] (transposed chunk)
    const int tid = threadIdx.x;
    const int tr = tid >> 4;            // 0..15 row group
    const int tc = tid & 15;            // 0..15 col group
    {   // load W once, coalesced
        const float4* Wv = (const float4*)W;
        float4* Wsv = (float4*)Ws;
        for (int i = tid; i < DIM * DIM / 4; i += 256) Wsv[i] = Wv[i];
    }
    const int n0 = blockIdx.x * 128;
    float acc[8][8] = {};
    for (int k0 = 0; k0 < DIM; k0 += BK) {
        __syncthreads();
        // stage A chunk: 128 rows x BK ks, transposed into As[k][r]
#pragma unroll
        for (int it = 0; it < 2; ++it) {
            int idx = it * 256 + tid;          // 0..511
            int row = idx & 127;
            int kq = idx >> 7;                 // 0..3
            int n = n0 + row;
            float4 v = make_float4(0.f, 0.f, 0.f, 0.f);
            float s = 0.f;
            if (n < N_NODES) {
                v = *(const float4*)(h + (size_t)n * DIM + k0 + kq * 4);
                s = rsqrtf(fmaxf(degp[n], 1.0f));
            }
            As[(kq * 4 + 0) * DIM + row] = v.x * s;
            As[(kq * 4 + 1) * DIM + row] = v.y * s;
            As[(kq * 4 + 2) * DIM + row] = v.z * s;
            As[(kq * 4 + 3) * DIM + row] = v.w * s;
        }
        __syncthreads();
#pragma unroll
        for (int k = 0; k < BK; ++k) {
            float4 a0 = *(const float4*)(As + k * DIM + tr * 4);
            float4 a1 = *(const float4*)(As + k * DIM + 64 + tr * 4);
            float4 b0 = *(const float4*)(Ws + (k0 + k) * DIM + tc * 4);
            float4 b1 = *(const float4*)(Ws + (k0 + k) * DIM + 64 + tc * 4);
            float av[8] = {a0.x, a0.y, a0.z, a0.w, a1.x, a1.y, a1.z, a1.w};
            float bv[8] = {b0.x, b0.y, b0.z, b0.w, b1.x, b1.y, b1.z, b1.w};
#pragma unroll
            for (int r = 0; r < 8; ++r)
#pragma unroll
                for (int c = 0; c < 8; ++c)
                    acc[r][c] = fmaf(av[r], bv[c], acc[r][c]);
        }
    }
#pragma unroll
    for (int r = 0; r < 8; ++r) {
        int rr = (r < 4) ? (tr * 4 + r) : (64 + tr * 4 + (r - 4));
        int n = n0 + rr;
        if (n < N_NODES) {
            float4 o0 = make_float4(acc[r][0], acc[r][1], acc[r][2], acc[r][3]);
            float4 o1 = make_float4(acc[r][4], acc[r][5], acc[r][6], acc[r][7]);
            *(float4*)(x + (size_t)n * DIM + tc * 4) = o0;
            *(float4*)(x + (size_t)n * DIM + 64 + tc * 4) = o1;
        }
    }
}

// ---------------- per-path scatter: z[dst] += x[src] ----------------
__global__ __launch_bounds__(256) void scatter_kernel(const int* __restrict__ src,
                                                      const int* __restrict__ dst,
                                                      const float* __restrict__ x,
                                                      float* __restrict__ zp) {
    int e = blockIdx.x * 2 + (threadIdx.x >> 7);
    int d = threadIdx.x & 127;
    if (e < N_EDGES) {
        int s = src[e];
        int t = dst[e];
        atomicAdd(&zp[(size_t)t * DIM + d], x[(size_t)s * DIM + d]);
    }
}

// ---------------- finalize: z = z * rsqrt(max(deg_in,1)) + b ----------------
__global__ void finalize_kernel(float* __restrict__ z, const float* __restrict__ deg_in,
                                const float* __restrict__ b_gc) {
    int i4 = blockIdx.x * blockDim.x + threadIdx.x;   // over P*N*D/4
    const int total4 = N_PATHS * N_NODES * DIM / 4;
    if (i4 < total4) {
        int d4 = i4 & 31;            // float4 index within row
        int pn = i4 >> 5;            // p*N + n
        int p = pn / N_NODES;
        float s = rsqrtf(fmaxf(deg_in[pn], 1.0f));
        float4 v = ((float4*)z)[i4];
        float4 b = *(const float4*)(b_gc + p * DIM + d4 * 4);
        v.x = v.x * s + b.x; v.y = v.y * s + b.y;
        v.z = v.z * s + b.z; v.w = v.w * s + b.w;
        ((float4*)z)[i4] = v;
    }
}

// ---------------- semantic score: tiled GEMM + tanh + w2-dot + reduce ----------------
__global__ __launch_bounds__(256, 2) void score_kernel(const float* __restrict__ z,
                                                       const float* __restrict__ w1,
                                                       const float* __restrict__ b1,
                                                       const float* __restrict__ w2,
                                                       float* __restrict__ score) {  // [3]
    __shared__ float Ws[DIM * DIM];
    __shared__ float As[BK * DIM];
    __shared__ float spath[N_PATHS];
    const int tid = threadIdx.x;
    const int tr = tid >> 4;
    const int tc = tid & 15;
    if (tid < N_PATHS) spath[tid] = 0.f;
    {
        const float4* Wv = (const float4*)w1;
        float4* Wsv = (float4*)Ws;
        for (int i = tid; i < DIM * DIM / 4; i += 256) Wsv[i] = Wv[i];
    }
    const int row0 = blockIdx.x * 128;
    const int NROWS = N_PATHS * N_NODES;
    float acc[8][8] = {};
    for (int k0 = 0; k0 < DIM; k0 += BK) {
        __syncthreads();
#pragma unroll
        for (int it = 0; it < 2; ++it) {
            int idx = it * 256 + tid;
            int row = idx & 127;
            int kq = idx >> 7;
            int rr = row0 + row;
            float4 v = make_float4(0.f, 0.f, 0.f, 0.f);
            if (rr < NROWS) v = *(const float4*)(z + (size_t)rr * DIM + k0 + kq * 4);
            As[(kq * 4 + 0) * DIM + row] = v.x;
            As[(kq * 4 + 1) * DIM + row] = v.y;
            As[(kq * 4 + 2) * DIM + row] = v.z;
            As[(kq * 4 + 3) * DIM + row] = v.w;
        }
        __syncthreads();
#pragma unroll
        for (int k = 0; k < BK; ++k) {
            float4 a0 = *(const float4*)(As + k * DIM + tr * 4);
            float4 a1 = *(const float4*)(As + k * DIM + 64 + tr * 4);
            float4 b0 = *(const float4*)(Ws + (k0 + k) * DIM + tc * 4);
            float4 b1v = *(const float4*)(Ws + (k0 + k) * DIM + 64 + tc * 4);
            float av[8] = {a0.x, a0.y, a0.z, a0.w, a1.x, a1.y, a1.z, a1.w};
            float bv[8] = {b0.x, b0.y, b0.z, b0.w, b1v.x, b1v.y, b1v.z, b1v.w};
#pragma unroll
            for (int r = 0; r < 8; ++r)
#pragma unroll
                for (int c = 0; c < 8; ++c)
                    acc[r][c] = fmaf(av[r], bv[c], acc[r][c]);
        }
    }
    // epilogue: tanh + w2 dot per row, reduce over col groups then block
    float4 bl0 = *(const float4*)(b1 + tc * 4);
    float4 bl1 = *(const float4*)(b1 + 64 + tc * 4);
    float4 wl0 = *(const float4*)(w2 + tc * 4);
    float4 wl1 = *(const float4*)(w2 + 64 + tc * 4);
    float bb[8] = {bl0.x, bl0.y, bl0.z, bl0.w, bl1.x, bl1.y, bl1.z, bl1.w};
    float ww[8] = {wl0.x, wl0.y, wl0.z, wl0.w, wl1.x, wl1.y, wl1.z, wl1.w};
    float sr[8];
#pragma unroll
    for (int r = 0; r < 8; ++r) {
        float s = 0.f;
#pragma unroll
        for (int c = 0; c < 8; ++c) s += tanh_fast(acc[r][c] + bb[c]) * ww[c];
        sr[r] = s;
    }
#pragma unroll
    for (int off = 1; off < 16; off <<= 1)
#pragma unroll
        for (int r = 0; r < 8; ++r) sr[r] += __shfl_xor(sr[r], off, 64);
    if (tc == 0) {
#pragma unroll
        for (int r = 0; r < 8; ++r) {
            int rr = (r < 4) ? (tr * 4 + r) : (64 + tr * 4 + (r - 4));
            int row = row0 + rr;
            if (row < NROWS) atomicAdd(&spath[row / N_NODES], sr[r]);
        }
    }
    __syncthreads();
    if (tid < N_PATHS) atomicAdd(&score[tid], spath[tid]);
}

// ---------------- beta = softmax(score / N) ----------------
__global__ void beta_kernel(const float* __restrict__ score, float* __restrict__ beta) {
    if (threadIdx.x == 0 && blockIdx.x == 0) {
        float a = score[0] / (float)N_NODES;
        float b = score[1] / (float)N_NODES;
        float c = score[2] / (float)N_NODES;
        float m = fmaxf(a, fmaxf(b, c));
        float e0 = expf(a - m), e1 = expf(b - m), e2 = expf(c - m);
        float s = e0 + e1 + e2;
        beta[0] = e0 / s; beta[1] = e1 / s; beta[2] = e2 / s;
    }
}

// ---------------- out = sum_p beta[p] * z[p] ----------------
__global__ void out_kernel(const float* __restrict__ z, const float* __restrict__ beta,
                           float* __restrict__ out) {
    int i = blockIdx.x * blockDim.x + threadIdx.x;  // over N*D/4
    const int nd4 = N_NODES * DIM / 4;
    if (i < nd4) {
        float b0 = beta[0], b1 = beta[1], b2 = beta[2];
        float4 z0 = ((const float4*)z)[i];
        float4 z1 = ((const float4*)z)[nd4 + i];
        float4 z2 = ((const float4*)z)[2 * (size_t)nd4 + i];
        float4 o;
        o.x = b0 * z0.x + b1 * z1.x + b2 * z2.x;
        o.y = b0 * z0.y + b1 * z1.y + b2 * z2.y;
        o.z = b0 * z0.z + b1 * z1.z + b2 * z2.z;
        o.w = b0 * z0.w + b1 * z1.w + b2 * z2.w;
        ((float4*)out)[i] = o;
    }
}

extern "C" void kernel_launch(void* const* d_in, const int* in_sizes, int n_in,
                              void* d_out, int out_size, void* d_ws, size_t ws_size,
                              hipStream_t stream) {
    const float* h    = (const float*)d_in[0];   // [N,128]
    const float* W_gc = (const float*)d_in[1];   // [3,128,128]
    const float* b_gc = (const float*)d_in[2];   // [3,128]
    const float* w1   = (const float*)d_in[3];   // [128,128]
    const float* b1   = (const float*)d_in[4];   // [128]
    const float* w2   = (const float*)d_in[5];   // [128]
    const int* esrc   = (const int*)d_in[6];     // [3,E]
    const int* edst   = (const int*)d_in[7];     // [3,E]
    float* out        = (float*)d_out;

    // workspace layout (floats)
    float* ws       = (float*)d_ws;
    float* deg_out  = ws;                                  // P*N
    float* deg_in   = deg_out + N_PATHS * N_NODES;         // P*N
    float* score    = deg_in + N_PATHS * N_NODES;          // 3
    float* beta     = score + N_PATHS;                     // 3
    const size_t Z_OFF = 300032;                           // aligned past deg/score/beta
    float* z        = ws + Z_OFF;                          // P*N*D
    float* x        = z + (size_t)N_PATHS * N_NODES * DIM; // N*D

    // zero: deg_out, deg_in, score (+beta pad) and z — one contiguous memset
    size_t zero_bytes = (Z_OFF + (size_t)N_PATHS * N_NODES * DIM) * sizeof(float);
    hipMemsetAsync(d_ws, 0, zero_bytes, stream);

    // degrees
    {
        int total = N_PATHS * N_EDGES;
        deg_kernel<<<(total + 255) / 256, 256, 0, stream>>>(esrc, edst, deg_out, deg_in);
    }

    // per-path: matmul then scatter (x reused; stream order serializes)
    for (int p = 0; p < N_PATHS; ++p) {
        gc_matmul<<<(N_NODES + 127) / 128, 256, 0, stream>>>(
            h, W_gc + (size_t)p * DIM * DIM, deg_out + (size_t)p * N_NODES, x);
        scatter_kernel<<<(N_EDGES + 1) / 2, 256, 0, stream>>>(
            esrc + (size_t)p * N_EDGES, edst + (size_t)p * N_EDGES, x,
            z + (size_t)p * N_NODES * DIM);
    }

    // finalize z
    {
        int total4 = N_PATHS * N_NODES * DIM / 4;
        finalize_kernel<<<(total4 + 255) / 256, 256, 0, stream>>>(z, deg_in, b_gc);
    }

    // semantic attention scores
    {
        int rows = N_PATHS * N_NODES;
        score_kernel<<<(rows + 127) / 128, 256, 0, stream>>>(z, w1, b1, w2, score);
    }

    beta_kernel<<<1, 64, 0, stream>>>(score, beta);

    {
        int nd4 = N_NODES * DIM / 4;
        out_kernel<<<(nd4 + 255) / 256, 256, 0, stream>>>(z, beta, out);
    }
}

// Round 3
// 773.671 us; speedup vs baseline: 3.1222x; 1.6599x over previous
//
#include <hip/hip_runtime.h>
#include <hip/hip_bf16.h>
#include <math.h>

#define N_NODES 50000
#define N_EDGES 600000
#define N_PATHS 3
#define DIM 128
#define BK 16
#define NROWS_ALL (N_PATHS * N_NODES)      // 150000
#define NE_ALL (N_PATHS * N_EDGES)         // 1800000
#define SCAN_BLOCKS ((NROWS_ALL + 1023) / 1024)   // 147

__device__ __forceinline__ float tanh_fast(float x) {
    return 1.0f - 2.0f / (__expf(2.0f * x) + 1.0f);
}

// ---------------- count: int histograms of src and dst ----------------
__global__ void count_kernel(const int* __restrict__ esrc, const int* __restrict__ edst,
                             int* __restrict__ cnt_out, int* __restrict__ cnt_in) {
    int i = blockIdx.x * blockDim.x + threadIdx.x;
    if (i < NE_ALL) {
        int p = i / N_EDGES;
        atomicAdd(&cnt_out[p * N_NODES + esrc[i]], 1);
        atomicAdd(&cnt_in [p * N_NODES + edst[i]], 1);
    }
}

// ---------------- scan pass1: block sums of cnt_in ----------------
__global__ __launch_bounds__(256) void scan_pass1(const int* __restrict__ cnt,
                                                  int* __restrict__ partial) {
    __shared__ int lds[256];
    int t = threadIdx.x;
    int base = blockIdx.x * 1024 + t * 4;
    int4 v = make_int4(0, 0, 0, 0);
    if (base < NROWS_ALL) v = *(const int4*)(cnt + base);
    int s = v.x + v.y + v.z + v.w;
    lds[t] = s; __syncthreads();
    for (int off = 1; off < 256; off <<= 1) {
        int u = (t >= off) ? lds[t - off] : 0;
        __syncthreads();
        lds[t] += u;
        __syncthreads();
    }
    if (t == 255) partial[blockIdx.x] = lds[255];
}

// ---------------- scan pass2: exclusive scan of partials (single block) ----------------
__global__ __launch_bounds__(256) void scan_pass2(int* __restrict__ partial) {
    __shared__ int lds[256];
    int t = threadIdx.x;
    int s = (t < SCAN_BLOCKS) ? partial[t] : 0;
    lds[t] = s; __syncthreads();
    for (int off = 1; off < 256; off <<= 1) {
        int u = (t >= off) ? lds[t - off] : 0;
        __syncthreads();
        lds[t] += u;
        __syncthreads();
    }
    if (t < SCAN_BLOCKS) partial[t] = lds[t] - s;   // exclusive
}

// ---------------- scan pass3: write exclusive scan -> rp and cursor ----------------
__global__ __launch_bounds__(256) void scan_pass3(const int* __restrict__ cnt,
                                                  const int* __restrict__ partial,
                                                  int* __restrict__ rp,
                                                  int* __restrict__ cursor) {
    __shared__ int lds[256];
    int t = threadIdx.x;
    int base = blockIdx.x * 1024 + t * 4;
    int4 v = make_int4(0, 0, 0, 0);
    if (base < NROWS_ALL) v = *(const int4*)(cnt + base);
    int s = v.x + v.y + v.z + v.w;
    lds[t] = s; __syncthreads();
    for (int off = 1; off < 256; off <<= 1) {
        int u = (t >= off) ? lds[t - off] : 0;
        __syncthreads();
        lds[t] += u;
        __syncthreads();
    }
    if (base < NROWS_ALL) {
        int run = partial[blockIdx.x] + lds[t] - s;
        int vv[4] = {v.x, v.y, v.z, v.w};
#pragma unroll
        for (int j = 0; j < 4; ++j) {
            rp[base + j] = run;
            cursor[base + j] = run;
            run += vv[j];
        }
    }
}

// ---------------- fill: CSR column (source id) array ----------------
__global__ void fill_kernel(const int* __restrict__ esrc, const int* __restrict__ edst,
                            int* __restrict__ cursor, int* __restrict__ col) {
    int i = blockIdx.x * blockDim.x + threadIdx.x;
    if (i < NE_ALL) {
        int p = i / N_EDGES;
        int pos = atomicAdd(&cursor[p * N_NODES + edst[i]], 1);
        col[pos] = esrc[i];
    }
}

// ---------------- gather: agg[pn] = sum_src h[src] * rsqrt(max(deg_out[src],1)) ----------------
__global__ __launch_bounds__(256) void gather_kernel(const int* __restrict__ rp,
                                                     const int* __restrict__ col,
                                                     const int* __restrict__ cnt_out,
                                                     const float* __restrict__ h,
                                                     float* __restrict__ z) {
    int wid = blockIdx.x * 4 + (threadIdx.x >> 6);
    int lane = threadIdx.x & 63;
    if (wid >= NROWS_ALL) return;
    int p = wid / N_NODES;
    int beg = rp[wid];
    int end = (wid == NROWS_ALL - 1) ? NE_ALL : rp[wid + 1];
    const int* cnt_p = cnt_out + p * N_NODES;
    float2 acc = make_float2(0.f, 0.f);
    for (int e = beg; e < end; ++e) {
        int s = col[e];                               // broadcast (same addr all lanes)
        float sc = rsqrtf(fmaxf((float)cnt_p[s], 1.0f));
        float2 v = *(const float2*)(h + (size_t)s * DIM + lane * 2);
        acc.x = fmaf(v.x, sc, acc.x);
        acc.y = fmaf(v.y, sc, acc.y);
    }
    *(float2*)(z + (size_t)wid * DIM + lane * 2) = acc;
}

// ---------------- fused GEMM: z_p = (agg_p @ W_p) * rsqrt(max(deg_in,1)) + b  (in-place) ----------------
__global__ __launch_bounds__(256, 2) void gemm_fused(float* __restrict__ zp,       // [N][128] in/out
                                                     const float* __restrict__ W,  // [128][128]
                                                     const int* __restrict__ rp,   // global
                                                     const float* __restrict__ bgc,// [128]
                                                     int pbase) {                  // p*N
    __shared__ float Ws[DIM * DIM];
    __shared__ float As[BK * DIM];
    const int tid = threadIdx.x;
    const int tr = tid >> 4;
    const int tc = tid & 15;
    {
        const float4* Wv = (const float4*)W;
        float4* Wsv = (float4*)Ws;
        for (int i = tid; i < DIM * DIM / 4; i += 256) Wsv[i] = Wv[i];
    }
    const int n0 = blockIdx.x * 128;
    float acc[8][8] = {};
    for (int k0 = 0; k0 < DIM; k0 += BK) {
        __syncthreads();
#pragma unroll
        for (int it = 0; it < 2; ++it) {
            int idx = it * 256 + tid;
            int row = idx & 127;
            int kq = idx >> 7;
            int n = n0 + row;
            float4 v = make_float4(0.f, 0.f, 0.f, 0.f);
            if (n < N_NODES) v = *(const float4*)(zp + (size_t)n * DIM + k0 + kq * 4);
            As[(kq * 4 + 0) * DIM + row] = v.x;
            As[(kq * 4 + 1) * DIM + row] = v.y;
            As[(kq * 4 + 2) * DIM + row] = v.z;
            As[(kq * 4 + 3) * DIM + row] = v.w;
        }
        __syncthreads();
#pragma unroll
        for (int k = 0; k < BK; ++k) {
            float4 a0 = *(const float4*)(As + k * DIM + tr * 4);
            float4 a1 = *(const float4*)(As + k * DIM + 64 + tr * 4);
            float4 b0 = *(const float4*)(Ws + (k0 + k) * DIM + tc * 4);
            float4 b1 = *(const float4*)(Ws + (k0 + k) * DIM + 64 + tc * 4);
            float av[8] = {a0.x, a0.y, a0.z, a0.w, a1.x, a1.y, a1.z, a1.w};
            float bv[8] = {b0.x, b0.y, b0.z, b0.w, b1.x, b1.y, b1.z, b1.w};
#pragma unroll
            for (int r = 0; r < 8; ++r)
#pragma unroll
                for (int c = 0; c < 8; ++c)
                    acc[r][c] = fmaf(av[r], bv[c], acc[r][c]);
        }
    }
    float4 bc0 = *(const float4*)(bgc + tc * 4);
    float4 bc1 = *(const float4*)(bgc + 64 + tc * 4);
#pragma unroll
    for (int r = 0; r < 8; ++r) {
        int rr = (r < 4) ? (tr * 4 + r) : (64 + tr * 4 + (r - 4));
        int n = n0 + rr;
        if (n < N_NODES) {
            int pn = pbase + n;
            int beg = rp[pn];
            int end = (pn == NROWS_ALL - 1) ? NE_ALL : rp[pn + 1];
            float s = rsqrtf(fmaxf((float)(end - beg), 1.0f));
            float4 o0, o1;
            o0.x = acc[r][0] * s + bc0.x; o0.y = acc[r][1] * s + bc0.y;
            o0.z = acc[r][2] * s + bc0.z; o0.w = acc[r][3] * s + bc0.w;
            o1.x = acc[r][4] * s + bc1.x; o1.y = acc[r][5] * s + bc1.y;
            o1.z = acc[r][6] * s + bc1.z; o1.w = acc[r][7] * s + bc1.w;
            *(float4*)(zp + (size_t)n * DIM + tc * 4) = o0;
            *(float4*)(zp + (size_t)n * DIM + 64 + tc * 4) = o1;
        }
    }
}

// ---------------- semantic score: tiled GEMM + tanh + w2-dot + reduce ----------------
__global__ __launch_bounds__(256, 2) void score_kernel(const float* __restrict__ z,
                                                       const float* __restrict__ w1,
                                                       const float* __restrict__ b1,
                                                       const float* __restrict__ w2,
                                                       float* __restrict__ score) {
    __shared__ float Ws[DIM * DIM];
    __shared__ float As[BK * DIM];
    __shared__ float spath[N_PATHS];
    const int tid = threadIdx.x;
    const int tr = tid >> 4;
    const int tc = tid & 15;
    if (tid < N_PATHS) spath[tid] = 0.f;
    {
        const float4* Wv = (const float4*)w1;
        float4* Wsv = (float4*)Ws;
        for (int i = tid; i < DIM * DIM / 4; i += 256) Wsv[i] = Wv[i];
    }
    const int row0 = blockIdx.x * 128;
    float acc[8][8] = {};
    for (int k0 = 0; k0 < DIM; k0 += BK) {
        __syncthreads();
#pragma unroll
        for (int it = 0; it < 2; ++it) {
            int idx = it * 256 + tid;
            int row = idx & 127;
            int kq = idx >> 7;
            int rr = row0 + row;
            float4 v = make_float4(0.f, 0.f, 0.f, 0.f);
            if (rr < NROWS_ALL) v = *(const float4*)(z + (size_t)rr * DIM + k0 + kq * 4);
            As[(kq * 4 + 0) * DIM + row] = v.x;
            As[(kq * 4 + 1) * DIM + row] = v.y;
            As[(kq * 4 + 2) * DIM + row] = v.z;
            As[(kq * 4 + 3) * DIM + row] = v.w;
        }
        __syncthreads();
#pragma unroll
        for (int k = 0; k < BK; ++k) {
            float4 a0 = *(const float4*)(As + k * DIM + tr * 4);
            float4 a1 = *(const float4*)(As + k * DIM + 64 + tr * 4);
            float4 b0 = *(const float4*)(Ws + (k0 + k) * DIM + tc * 4);
            float4 b1v = *(const float4*)(Ws + (k0 + k) * DIM + 64 + tc * 4);
            float av[8] = {a0.x, a0.y, a0.z, a0.w, a1.x, a1.y, a1.z, a1.w};
            float bv[8] = {b0.x, b0.y, b0.z, b0.w, b1v.x, b1v.y, b1v.z, b1v.w};
#pragma unroll
            for (int r = 0; r < 8; ++r)
#pragma unroll
                for (int c = 0; c < 8; ++c)
                    acc[r][c] = fmaf(av[r], bv[c], acc[r][c]);
        }
    }
    float4 bl0 = *(const float4*)(b1 + tc * 4);
    float4 bl1 = *(const float4*)(b1 + 64 + tc * 4);
    float4 wl0 = *(const float4*)(w2 + tc * 4);
    float4 wl1 = *(const float4*)(w2 + 64 + tc * 4);
    float bb[8] = {bl0.x, bl0.y, bl0.z, bl0.w, bl1.x, bl1.y, bl1.z, bl1.w};
    float ww[8] = {wl0.x, wl0.y, wl0.z, wl0.w, wl1.x, wl1.y, wl1.z, wl1.w};
    float sr[8];
#pragma unroll
    for (int r = 0; r < 8; ++r) {
        float s = 0.f;
#pragma unroll
        for (int c = 0; c < 8; ++c) s += tanh_fast(acc[r][c] + bb[c]) * ww[c];
        sr[r] = s;
    }
#pragma unroll
    for (int off = 1; off < 16; off <<= 1)
#pragma unroll
        for (int r = 0; r < 8; ++r) sr[r] += __shfl_xor(sr[r], off, 64);
    if (tc == 0) {
#pragma unroll
        for (int r = 0; r < 8; ++r) {
            int rr = (r < 4) ? (tr * 4 + r) : (64 + tr * 4 + (r - 4));
            int row = row0 + rr;
            if (row < NROWS_ALL) atomicAdd(&spath[row / N_NODES], sr[r]);
        }
    }
    __syncthreads();
    if (tid < N_PATHS) atomicAdd(&score[tid], spath[tid]);
}

// ---------------- beta = softmax(score / N) ----------------
__global__ void beta_kernel(const float* __restrict__ score, float* __restrict__ beta) {
    if (threadIdx.x == 0 && blockIdx.x == 0) {
        float a = score[0] / (float)N_NODES;
        float b = score[1] / (float)N_NODES;
        float c = score[2] / (float)N_NODES;
        float m = fmaxf(a, fmaxf(b, c));
        float e0 = expf(a - m), e1 = expf(b - m), e2 = expf(c - m);
        float s = e0 + e1 + e2;
        beta[0] = e0 / s; beta[1] = e1 / s; beta[2] = e2 / s;
    }
}

// ---------------- out = sum_p beta[p] * z[p] ----------------
__global__ void out_kernel(const float* __restrict__ z, const float* __restrict__ beta,
                           float* __restrict__ out) {
    int i = blockIdx.x * blockDim.x + threadIdx.x;
    const int nd4 = N_NODES * DIM / 4;
    if (i < nd4) {
        float b0 = beta[0], b1 = beta[1], b2 = beta[2];
        float4 z0 = ((const float4*)z)[i];
        float4 z1 = ((const float4*)z)[nd4 + i];
        float4 z2 = ((const float4*)z)[2 * (size_t)nd4 + i];
        float4 o;
        o.x = b0 * z0.x + b1 * z1.x + b2 * z2.x;
        o.y = b0 * z0.y + b1 * z1.y + b2 * z2.y;
        o.z = b0 * z0.z + b1 * z1.z + b2 * z2.z;
        o.w = b0 * z0.w + b1 * z1.w + b2 * z2.w;
        ((float4*)out)[i] = o;
    }
}

extern "C" void kernel_launch(void* const* d_in, const int* in_sizes, int n_in,
                              void* d_out, int out_size, void* d_ws, size_t ws_size,
                              hipStream_t stream) {
    const float* h    = (const float*)d_in[0];
    const float* W_gc = (const float*)d_in[1];
    const float* b_gc = (const float*)d_in[2];
    const float* w1   = (const float*)d_in[3];
    const float* b1   = (const float*)d_in[4];
    const float* w2   = (const float*)d_in[5];
    const int* esrc   = (const int*)d_in[6];
    const int* edst   = (const int*)d_in[7];
    float* out        = (float*)d_out;

    // workspace layout (4-byte word offsets)
    int*   cnt_out = (int*)d_ws;                         // 150000
    int*   cnt_in  = cnt_out + NROWS_ALL;                // 150000
    float* score   = (float*)d_ws + 300000;              // 3
    float* beta    = score + 4;                          // 3 (pad)
    int*   partial = (int*)d_ws + 300032;                // 256
    int*   rp      = (int*)d_ws + 300288;                // 150000
    int*   cursor  = (int*)d_ws + 450288;                // 150000
    int*   col     = (int*)d_ws + 600288;                // 1800000
    float* z       = (float*)d_ws + 2400288;             // 19200000

    // zero cnt_out + cnt_in + score/beta region
    hipMemsetAsync(d_ws, 0, 300032 * sizeof(int), stream);

    count_kernel<<<(NE_ALL + 255) / 256, 256, 0, stream>>>(esrc, edst, cnt_out, cnt_in);

    scan_pass1<<<SCAN_BLOCKS, 256, 0, stream>>>(cnt_in, partial);
    scan_pass2<<<1, 256, 0, stream>>>(partial);
    scan_pass3<<<SCAN_BLOCKS, 256, 0, stream>>>(cnt_in, partial, rp, cursor);

    fill_kernel<<<(NE_ALL + 255) / 256, 256, 0, stream>>>(esrc, edst, cursor, col);

    gather_kernel<<<(NROWS_ALL + 3) / 4, 256, 0, stream>>>(rp, col, cnt_out, h, z);

    for (int p = 0; p < N_PATHS; ++p) {
        gemm_fused<<<(N_NODES + 127) / 128, 256, 0, stream>>>(
            z + (size_t)p * N_NODES * DIM, W_gc + (size_t)p * DIM * DIM,
            rp, b_gc + (size_t)p * DIM, p * N_NODES);
    }

    score_kernel<<<(NROWS_ALL + 127) / 128, 256, 0, stream>>>(z, w1, b1, w2, score);

    beta_kernel<<<1, 64, 0, stream>>>(score, beta);

    out_kernel<<<(N_NODES * DIM / 4 + 255) / 256, 256, 0, stream>>>(z, beta, out);
}

// Round 4
// 657.041 us; speedup vs baseline: 3.6765x; 1.1775x over previous
//
#include <hip/hip_runtime.h>
#include <math.h>

#define N_NODES 50000
#define N_EDGES 600000
#define N_PATHS 3
#define DIM 128
#define NROWS_ALL (N_PATHS * N_NODES)      // 150000
#define NE_ALL (N_PATHS * N_EDGES)         // 1800000
#define SCAN_BLOCKS ((NROWS_ALL + 1023) / 1024)   // 147

typedef __attribute__((ext_vector_type(8))) short bf16x8;
typedef __attribute__((ext_vector_type(4))) float f32x4;

__device__ __forceinline__ unsigned short f2bf(float f) {
    unsigned u = __float_as_uint(f);
    u += 0x7FFF + ((u >> 16) & 1);          // round-to-nearest-even
    return (unsigned short)(u >> 16);
}
__device__ __forceinline__ float tanh_fast(float x) {
    return 1.0f - 2.0f / (__expf(2.0f * x) + 1.0f);
}

// ---------------- convert h -> bf16 ----------------
__global__ void conv_h(const float* __restrict__ h, unsigned int* __restrict__ hb) {
    int i = blockIdx.x * blockDim.x + threadIdx.x;      // 8 elems per thread
    if (i >= N_NODES * DIM / 8) return;
    const float4* h4 = (const float4*)h;
    float4 a = h4[2 * i], b = h4[2 * i + 1];
    uint4 o;
    o.x = f2bf(a.x) | ((unsigned)f2bf(a.y) << 16);
    o.y = f2bf(a.z) | ((unsigned)f2bf(a.w) << 16);
    o.z = f2bf(b.x) | ((unsigned)f2bf(b.y) << 16);
    o.w = f2bf(b.z) | ((unsigned)f2bf(b.w) << 16);
    ((uint4*)hb)[i] = o;
}

// ---------------- convert + transpose weights -> bf16 [n][k] ----------------
__global__ void conv_w(const float* __restrict__ W_gc, const float* __restrict__ w1,
                       unsigned short* __restrict__ Wtb, unsigned short* __restrict__ w1tb) {
    int i = blockIdx.x * blockDim.x + threadIdx.x;
    if (i < N_PATHS * DIM * DIM) {
        int p = i / (DIM * DIM), r = i % (DIM * DIM);
        int n = r / DIM, k = r % DIM;
        Wtb[i] = f2bf(W_gc[p * DIM * DIM + k * DIM + n]);
    } else if (i < (N_PATHS + 1) * DIM * DIM) {
        int r = i - N_PATHS * DIM * DIM;
        int n = r / DIM, k = r % DIM;
        w1tb[r] = f2bf(w1[k * DIM + n]);
    }
}

// ---------------- count: int histograms of src and dst ----------------
__global__ void count_kernel(const int* __restrict__ esrc, const int* __restrict__ edst,
                             int* __restrict__ cnt_out, int* __restrict__ cnt_in) {
    int i = blockIdx.x * blockDim.x + threadIdx.x;
    if (i < NE_ALL) {
        int p = i / N_EDGES;
        atomicAdd(&cnt_out[p * N_NODES + esrc[i]], 1);
        atomicAdd(&cnt_in [p * N_NODES + edst[i]], 1);
    }
}

// ---------------- per-src scale table ----------------
__global__ void scale_kernel(const int* __restrict__ cnt_out, float* __restrict__ sc_out) {
    int i = blockIdx.x * blockDim.x + threadIdx.x;
    if (i < NROWS_ALL) sc_out[i] = rsqrtf(fmaxf((float)cnt_out[i], 1.0f));
}

// ---------------- scan pass1: block sums of cnt_in ----------------
__global__ __launch_bounds__(256) void scan_pass1(const int* __restrict__ cnt,
                                                  int* __restrict__ partial) {
    __shared__ int lds[256];
    int t = threadIdx.x;
    int base = blockIdx.x * 1024 + t * 4;
    int4 v = make_int4(0, 0, 0, 0);
    if (base < NROWS_ALL) v = *(const int4*)(cnt + base);
    int s = v.x + v.y + v.z + v.w;
    lds[t] = s; __syncthreads();
    for (int off = 1; off < 256; off <<= 1) {
        int u = (t >= off) ? lds[t - off] : 0;
        __syncthreads();
        lds[t] += u;
        __syncthreads();
    }
    if (t == 255) partial[blockIdx.x] = lds[255];
}

// ---------------- scan pass2: exclusive scan of partials ----------------
__global__ __launch_bounds__(256) void scan_pass2(int* __restrict__ partial) {
    __shared__ int lds[256];
    int t = threadIdx.x;
    int s = (t < SCAN_BLOCKS) ? partial[t] : 0;
    lds[t] = s; __syncthreads();
    for (int off = 1; off < 256; off <<= 1) {
        int u = (t >= off) ? lds[t - off] : 0;
        __syncthreads();
        lds[t] += u;
        __syncthreads();
    }
    if (t < SCAN_BLOCKS) partial[t] = lds[t] - s;
}

// ---------------- scan pass3: write exclusive scan -> cursor ----------------
__global__ __launch_bounds__(256) void scan_pass3(const int* __restrict__ cnt,
                                                  const int* __restrict__ partial,
                                                  int* __restrict__ cursor) {
    __shared__ int lds[256];
    int t = threadIdx.x;
    int base = blockIdx.x * 1024 + t * 4;
    int4 v = make_int4(0, 0, 0, 0);
    if (base < NROWS_ALL) v = *(const int4*)(cnt + base);
    int s = v.x + v.y + v.z + v.w;
    lds[t] = s; __syncthreads();
    for (int off = 1; off < 256; off <<= 1) {
        int u = (t >= off) ? lds[t - off] : 0;
        __syncthreads();
        lds[t] += u;
        __syncthreads();
    }
    if (base < NROWS_ALL) {
        int run = partial[blockIdx.x] + lds[t] - s;
        int vv[4] = {v.x, v.y, v.z, v.w};
#pragma unroll
        for (int j = 0; j < 4; ++j) { cursor[base + j] = run; run += vv[j]; }
    }
}

// ---------------- fill: CSR column (ushort src id) ----------------
__global__ void fill_kernel(const int* __restrict__ esrc, const int* __restrict__ edst,
                            int* __restrict__ cursor, unsigned short* __restrict__ col) {
    int i = blockIdx.x * blockDim.x + threadIdx.x;
    if (i < NE_ALL) {
        int p = i / N_EDGES;
        int pos = atomicAdd(&cursor[p * N_NODES + edst[i]], 1);
        col[pos] = (unsigned short)esrc[i];
    }
}

// ---------------- gather (bf16 h): aggb[pn] = bf16( sum_src h[src]*sc_out[src] ) ----------------
// after fill, cursor[pn] = end pointer; beg = cursor[pn-1] (0 for pn==0)
__global__ __launch_bounds__(256) void gather_kernel(const int* __restrict__ cursor,
                                                     const unsigned short* __restrict__ col,
                                                     const float* __restrict__ sc_out,
                                                     const unsigned int* __restrict__ hb,
                                                     unsigned int* __restrict__ aggb) {
    int wid = blockIdx.x * 4 + (threadIdx.x >> 6);
    int lane = threadIdx.x & 63;
    if (wid >= NROWS_ALL) return;
    int p = wid / N_NODES;
    int beg = (wid == 0) ? 0 : cursor[wid - 1];
    int end = cursor[wid];
    const float* scp = sc_out + p * N_NODES;
    float ax = 0.f, ay = 0.f;
    for (int e = beg; e < end; ++e) {
        int s = col[e];                                  // broadcast
        float sc = scp[s];
        unsigned v = hb[s * 64 + lane];                  // 2 bf16
        float vx = __uint_as_float(v << 16);
        float vy = __uint_as_float(v & 0xFFFF0000u);
        ax = fmaf(vx, sc, ax);
        ay = fmaf(vy, sc, ay);
    }
    aggb[(size_t)wid * 64 + lane] = f2bf(ax) | ((unsigned)f2bf(ay) << 16);
}

// ---------------- MFMA GEMM: z_p = (agg_p @ W_p) * rsqrt(max(deg_in,1)) + b ----------------
// one wave per 16 rows; block = 4 waves = 64 rows; no LDS, no barriers.
__global__ __launch_bounds__(256) void gemm_fused(const unsigned short* __restrict__ aggb_p,
                                                  const unsigned short* __restrict__ Wtb_p,
                                                  const int* __restrict__ cnt_in_p,
                                                  const float* __restrict__ bgc,
                                                  float* __restrict__ zp) {
    int wave = threadIdx.x >> 6, lane = threadIdx.x & 63;
    int m = lane & 15, quad = lane >> 4;
    int r0 = blockIdx.x * 64 + wave * 16;
    if (r0 >= N_NODES) return;                 // N_NODES % 16 == 0: whole-wave guard
    const short* ab = (const short*)aggb_p;
    bf16x8 a[4];
#pragma unroll
    for (int q = 0; q < 4; ++q)
        a[q] = *(const bf16x8*)(ab + (size_t)(r0 + m) * DIM + q * 32 + quad * 8);
    float s[4];
#pragma unroll
    for (int rg = 0; rg < 4; ++rg)
        s[rg] = rsqrtf(fmaxf((float)cnt_in_p[r0 + quad * 4 + rg], 1.0f));
    const short* wb = (const short*)Wtb_p;
#pragma unroll
    for (int n0 = 0; n0 < 8; ++n0) {
        f32x4 acc = {0.f, 0.f, 0.f, 0.f};
#pragma unroll
        for (int q = 0; q < 4; ++q) {
            bf16x8 b = *(const bf16x8*)(wb + (n0 * 16 + m) * DIM + q * 32 + quad * 8);
            acc = __builtin_amdgcn_mfma_f32_16x16x32_bf16(a[q], b, acc, 0, 0, 0);
        }
        int colj = n0 * 16 + m;
        float bias = bgc[colj];
#pragma unroll
        for (int rg = 0; rg < 4; ++rg) {       // C/D: row=quad*4+rg, col=m
            int r = r0 + quad * 4 + rg;
            zp[(size_t)r * DIM + colj] = acc[rg] * s[rg] + bias;
        }
    }
}

// ---------------- score: MFMA z@w1t + tanh + w2-dot + reduce ----------------
__global__ __launch_bounds__(256) void score_kernel(const float* __restrict__ z,
                                                    const unsigned short* __restrict__ w1tb,
                                                    const float* __restrict__ b1,
                                                    const float* __restrict__ w2,
                                                    float* __restrict__ score) {
    __shared__ float spath[N_PATHS];
    int tid = threadIdx.x;
    int wave = tid >> 6, lane = tid & 63;
    int m = lane & 15, quad = lane >> 4;
    if (tid < N_PATHS) spath[tid] = 0.f;
    int r0 = blockIdx.x * 64 + wave * 16;
    bool valid = (r0 < NROWS_ALL);             // NROWS_ALL % 16 == 0
    int rbase = valid ? r0 : 0;
    bf16x8 a[4];
#pragma unroll
    for (int q = 0; q < 4; ++q) {
        const float* zr = z + (size_t)(rbase + m) * DIM + q * 32 + quad * 8;
        float4 f0 = *(const float4*)zr;
        float4 f1 = *(const float4*)(zr + 4);
        bf16x8 t;
        t[0] = f2bf(f0.x); t[1] = f2bf(f0.y); t[2] = f2bf(f0.z); t[3] = f2bf(f0.w);
        t[4] = f2bf(f1.x); t[5] = f2bf(f1.y); t[6] = f2bf(f1.z); t[7] = f2bf(f1.w);
        a[q] = t;
    }
    const short* wb = (const short*)w1tb;
    float rsum[4] = {0.f, 0.f, 0.f, 0.f};
#pragma unroll
    for (int n0 = 0; n0 < 8; ++n0) {
        f32x4 acc = {0.f, 0.f, 0.f, 0.f};
#pragma unroll
        for (int q = 0; q < 4; ++q) {
            bf16x8 b = *(const bf16x8*)(wb + (n0 * 16 + m) * DIM + q * 32 + quad * 8);
            acc = __builtin_amdgcn_mfma_f32_16x16x32_bf16(a[q], b, acc, 0, 0, 0);
        }
        int colj = n0 * 16 + m;
        float bj = b1[colj], wj = w2[colj];
#pragma unroll
        for (int rg = 0; rg < 4; ++rg)
            rsum[rg] += tanh_fast(acc[rg] + bj) * wj;
    }
#pragma unroll
    for (int off = 1; off < 16; off <<= 1)
#pragma unroll
        for (int rg = 0; rg < 4; ++rg) rsum[rg] += __shfl_xor(rsum[rg], off, 64);
    __syncthreads();
    if (valid && m == 0) {
        int p = r0 / N_NODES;                  // 16-band never crosses a path boundary
        atomicAdd(&spath[p], rsum[0] + rsum[1] + rsum[2] + rsum[3]);
    }
    __syncthreads();
    if (tid < N_PATHS) atomicAdd(&score[tid], spath[tid]);
}

// ---------------- beta = softmax(score / N) ----------------
__global__ void beta_kernel(const float* __restrict__ score, float* __restrict__ beta) {
    if (threadIdx.x == 0 && blockIdx.x == 0) {
        float a = score[0] / (float)N_NODES;
        float b = score[1] / (float)N_NODES;
        float c = score[2] / (float)N_NODES;
        float mx = fmaxf(a, fmaxf(b, c));
        float e0 = expf(a - mx), e1 = expf(b - mx), e2 = expf(c - mx);
        float s = e0 + e1 + e2;
        beta[0] = e0 / s; beta[1] = e1 / s; beta[2] = e2 / s;
    }
}

// ---------------- out = sum_p beta[p] * z[p] ----------------
__global__ void out_kernel(const float* __restrict__ z, const float* __restrict__ beta,
                           float* __restrict__ out) {
    int i = blockIdx.x * blockDim.x + threadIdx.x;
    const int nd4 = N_NODES * DIM / 4;
    if (i < nd4) {
        float b0 = beta[0], b1 = beta[1], b2 = beta[2];
        float4 z0 = ((const float4*)z)[i];
        float4 z1 = ((const float4*)z)[nd4 + i];
        float4 z2 = ((const float4*)z)[2 * (size_t)nd4 + i];
        float4 o;
        o.x = b0 * z0.x + b1 * z1.x + b2 * z2.x;
        o.y = b0 * z0.y + b1 * z1.y + b2 * z2.y;
        o.z = b0 * z0.z + b1 * z1.z + b2 * z2.z;
        o.w = b0 * z0.w + b1 * z1.w + b2 * z2.w;
        ((float4*)out)[i] = o;
    }
}

extern "C" void kernel_launch(void* const* d_in, const int* in_sizes, int n_in,
                              void* d_out, int out_size, void* d_ws, size_t ws_size,
                              hipStream_t stream) {
    const float* h    = (const float*)d_in[0];
    const float* W_gc = (const float*)d_in[1];
    const float* b_gc = (const float*)d_in[2];
    const float* w1   = (const float*)d_in[3];
    const float* b1   = (const float*)d_in[4];
    const float* w2   = (const float*)d_in[5];
    const int* esrc   = (const int*)d_in[6];
    const int* edst   = (const int*)d_in[7];
    float* out        = (float*)d_out;

    // workspace layout (4-byte word offsets)
    int*   cnt_out = (int*)d_ws;                                // 150000
    int*   cnt_in  = cnt_out + NROWS_ALL;                       // 150000
    float* score   = (float*)d_ws + 300000;                     // 4
    float* beta    = (float*)d_ws + 300004;                     // 4 (+pad)
    int*   partial = (int*)d_ws + 300032;                       // 256
    float* sc_out  = (float*)d_ws + 300288;                     // 150000
    unsigned short* Wtb  = (unsigned short*)((int*)d_ws + 450288);   // 24576 words
    unsigned short* w1tb = (unsigned short*)((int*)d_ws + 474864);   // 8192 words
    unsigned int*   aggb = (unsigned int*)((int*)d_ws + 483056);     // 9.6M words
    float* z       = (float*)d_ws + 10083056;                   // 19.2M words (fp32)
    // region overlapped by z after gather completes (dead by then):
    int*   cursor  = (int*)d_ws + 10083056;                     // 150000
    unsigned short* col = (unsigned short*)((int*)d_ws + 10233056);  // 900000 words
    unsigned int*   hb  = (unsigned int*)((int*)d_ws + 11133056);    // 3.2M words

    // zero cnt_out, cnt_in, score/beta, partial
    hipMemsetAsync(d_ws, 0, 300288 * sizeof(int), stream);

    conv_h<<<(N_NODES * DIM / 8 + 255) / 256, 256, 0, stream>>>(h, hb);
    conv_w<<<((N_PATHS + 1) * DIM * DIM + 255) / 256, 256, 0, stream>>>(W_gc, w1, Wtb, w1tb);

    count_kernel<<<(NE_ALL + 255) / 256, 256, 0, stream>>>(esrc, edst, cnt_out, cnt_in);
    scale_kernel<<<(NROWS_ALL + 255) / 256, 256, 0, stream>>>(cnt_out, sc_out);

    scan_pass1<<<SCAN_BLOCKS, 256, 0, stream>>>(cnt_in, partial);
    scan_pass2<<<1, 256, 0, stream>>>(partial);
    scan_pass3<<<SCAN_BLOCKS, 256, 0, stream>>>(cnt_in, partial, cursor);

    fill_kernel<<<(NE_ALL + 255) / 256, 256, 0, stream>>>(esrc, edst, cursor, col);

    gather_kernel<<<(NROWS_ALL + 3) / 4, 256, 0, stream>>>(cursor, col, sc_out, hb, aggb);

    for (int p = 0; p < N_PATHS; ++p) {
        gemm_fused<<<(N_NODES + 63) / 64, 256, 0, stream>>>(
            (const unsigned short*)aggb + (size_t)p * N_NODES * DIM,
            Wtb + (size_t)p * DIM * DIM,
            cnt_in + p * N_NODES,
            b_gc + (size_t)p * DIM,
            z + (size_t)p * N_NODES * DIM);
    }

    score_kernel<<<(NROWS_ALL + 63) / 64, 256, 0, stream>>>(z, w1tb, b1, w2, score);

    beta_kernel<<<1, 64, 0, stream>>>(score, beta);

    out_kernel<<<(N_NODES * DIM / 4 + 255) / 256, 256, 0, stream>>>(z, beta, out);
}

// Round 6
// 554.617 us; speedup vs baseline: 4.3554x; 1.1847x over previous
//
#include <hip/hip_runtime.h>
#include <math.h>

#define N_NODES 50000
#define N_EDGES 600000
#define N_PATHS 3
#define DIM 128
#define NROWS_ALL (N_PATHS * N_NODES)      // 150000
#define NE_ALL (N_PATHS * N_EDGES)         // 1800000
#define SCAN_BLOCKS ((NROWS_ALL + 1023) / 1024)   // 147
#define NWAVES_SC (NROWS_ALL / 16)         // 9375

typedef __attribute__((ext_vector_type(8))) short bf16x8;
typedef __attribute__((ext_vector_type(4))) float f32x4;

__device__ __forceinline__ unsigned short f2bf(float f) {
    unsigned u = __float_as_uint(f);
    u += 0x7FFF + ((u >> 16) & 1);          // round-to-nearest-even
    return (unsigned short)(u >> 16);
}
__device__ __forceinline__ float tanh_fast(float x) {
    return 1.0f - 2.0f / (__expf(2.0f * x) + 1.0f);
}

// ---------------- convert h -> bf16 ----------------
__global__ void conv_h(const float* __restrict__ h, unsigned int* __restrict__ hb) {
    int i = blockIdx.x * blockDim.x + threadIdx.x;      // 8 elems per thread
    if (i >= N_NODES * DIM / 8) return;
    const float4* h4 = (const float4*)h;
    float4 a = h4[2 * i], b = h4[2 * i + 1];
    uint4 o;
    o.x = f2bf(a.x) | ((unsigned)f2bf(a.y) << 16);
    o.y = f2bf(a.z) | ((unsigned)f2bf(a.w) << 16);
    o.z = f2bf(b.x) | ((unsigned)f2bf(b.y) << 16);
    o.w = f2bf(b.z) | ((unsigned)f2bf(b.w) << 16);
    ((uint4*)hb)[i] = o;
}

// ---------------- convert + transpose weights -> bf16 [n][k] ----------------
__global__ void conv_w(const float* __restrict__ W_gc, const float* __restrict__ w1,
                       unsigned short* __restrict__ Wtb, unsigned short* __restrict__ w1tb) {
    int i = blockIdx.x * blockDim.x + threadIdx.x;
    if (i < N_PATHS * DIM * DIM) {
        int p = i / (DIM * DIM), r = i % (DIM * DIM);
        int n = r / DIM, k = r % DIM;
        Wtb[i] = f2bf(W_gc[p * DIM * DIM + k * DIM + n]);
    } else if (i < (N_PATHS + 1) * DIM * DIM) {
        int r = i - N_PATHS * DIM * DIM;
        int n = r / DIM, k = r % DIM;
        w1tb[r] = f2bf(w1[k * DIM + n]);
    }
}

// ---------------- count: int histograms of src and dst ----------------
__global__ void count_kernel(const int* __restrict__ esrc, const int* __restrict__ edst,
                             int* __restrict__ cnt_out, int* __restrict__ cnt_in) {
    int i = blockIdx.x * blockDim.x + threadIdx.x;
    if (i < NE_ALL) {
        int p = i / N_EDGES;
        atomicAdd(&cnt_out[p * N_NODES + esrc[i]], 1);
        atomicAdd(&cnt_in [p * N_NODES + edst[i]], 1);
    }
}

// ---------------- per-src scale table ----------------
__global__ void scale_kernel(const int* __restrict__ cnt_out, float* __restrict__ sc_out) {
    int i = blockIdx.x * blockDim.x + threadIdx.x;
    if (i < NROWS_ALL) sc_out[i] = rsqrtf(fmaxf((float)cnt_out[i], 1.0f));
}

// ---------------- scan pass1: block sums of cnt_in ----------------
__global__ __launch_bounds__(256) void scan_pass1(const int* __restrict__ cnt,
                                                  int* __restrict__ partial) {
    __shared__ int lds[256];
    int t = threadIdx.x;
    int base = blockIdx.x * 1024 + t * 4;
    int4 v = make_int4(0, 0, 0, 0);
    if (base < NROWS_ALL) v = *(const int4*)(cnt + base);
    int s = v.x + v.y + v.z + v.w;
    lds[t] = s; __syncthreads();
    for (int off = 1; off < 256; off <<= 1) {
        int u = (t >= off) ? lds[t - off] : 0;
        __syncthreads();
        lds[t] += u;
        __syncthreads();
    }
    if (t == 255) partial[blockIdx.x] = lds[255];
}

// ---------------- scan pass2: exclusive scan of partials ----------------
__global__ __launch_bounds__(256) void scan_pass2(int* __restrict__ partial) {
    __shared__ int lds[256];
    int t = threadIdx.x;
    int s = (t < SCAN_BLOCKS) ? partial[t] : 0;
    lds[t] = s; __syncthreads();
    for (int off = 1; off < 256; off <<= 1) {
        int u = (t >= off) ? lds[t - off] : 0;
        __syncthreads();
        lds[t] += u;
        __syncthreads();
    }
    if (t < SCAN_BLOCKS) partial[t] = lds[t] - s;
}

// ---------------- scan pass3: write exclusive scan -> cursor ----------------
__global__ __launch_bounds__(256) void scan_pass3(const int* __restrict__ cnt,
                                                  const int* __restrict__ partial,
                                                  int* __restrict__ cursor) {
    __shared__ int lds[256];
    int t = threadIdx.x;
    int base = blockIdx.x * 1024 + t * 4;
    int4 v = make_int4(0, 0, 0, 0);
    if (base < NROWS_ALL) v = *(const int4*)(cnt + base);
    int s = v.x + v.y + v.z + v.w;
    lds[t] = s; __syncthreads();
    for (int off = 1; off < 256; off <<= 1) {
        int u = (t >= off) ? lds[t - off] : 0;
        __syncthreads();
        lds[t] += u;
        __syncthreads();
    }
    if (base < NROWS_ALL) {
        int run = partial[blockIdx.x] + lds[t] - s;
        int vv[4] = {v.x, v.y, v.z, v.w};
#pragma unroll
        for (int j = 0; j < 4; ++j) { cursor[base + j] = run; run += vv[j]; }
    }
}

// ---------------- fill: CSR column (ushort src id) ----------------
__global__ void fill_kernel(const int* __restrict__ esrc, const int* __restrict__ edst,
                            int* __restrict__ cursor, unsigned short* __restrict__ col) {
    int i = blockIdx.x * blockDim.x + threadIdx.x;
    if (i < NE_ALL) {
        int p = i / N_EDGES;
        int pos = atomicAdd(&cursor[p * N_NODES + edst[i]], 1);
        col[pos] = (unsigned short)esrc[i];
    }
}

// ---------------- gather: 4 edge-slots x 16 lanes x 8 dims ----------------
// aggb[pn] = bf16( sum_src h[src]*sc_out[src] )
// NOTE: one row = 128 bf16 = 256 B = 16 uint4 -> row stride is 16 (R5 bug was 8).
__global__ __launch_bounds__(256) void gather_kernel(const int* __restrict__ cursor,
                                                     const unsigned short* __restrict__ col,
                                                     const float* __restrict__ sc_out,
                                                     const uint4* __restrict__ hb4,
                                                     uint4* __restrict__ aggb4) {
    int wid = blockIdx.x * 4 + (threadIdx.x >> 6);
    int lane = threadIdx.x & 63;
    int ss = lane >> 4;          // edge slot 0..3
    int ln = lane & 15;          // dim group: dims [ln*8, ln*8+8)
    if (wid >= NROWS_ALL) return;
    int p = wid / N_NODES;
    int beg = (wid == 0) ? 0 : cursor[wid - 1];
    int end = cursor[wid];
    const float* scp = sc_out + p * N_NODES;
    float acc[8] = {};
    for (int e = beg + ss; e < end; e += 4) {
        int s = col[e];                              // uniform within slot
        float sc = scp[s];
        uint4 v = hb4[s * 16 + ln];                  // 16 B = 8 bf16 (stride 16/row)
        acc[0] = fmaf(__uint_as_float(v.x << 16),        sc, acc[0]);
        acc[1] = fmaf(__uint_as_float(v.x & 0xFFFF0000u), sc, acc[1]);
        acc[2] = fmaf(__uint_as_float(v.y << 16),        sc, acc[2]);
        acc[3] = fmaf(__uint_as_float(v.y & 0xFFFF0000u), sc, acc[3]);
        acc[4] = fmaf(__uint_as_float(v.z << 16),        sc, acc[4]);
        acc[5] = fmaf(__uint_as_float(v.z & 0xFFFF0000u), sc, acc[5]);
        acc[6] = fmaf(__uint_as_float(v.w << 16),        sc, acc[6]);
        acc[7] = fmaf(__uint_as_float(v.w & 0xFFFF0000u), sc, acc[7]);
    }
    // reduce across the 4 slots
#pragma unroll
    for (int j = 0; j < 8; ++j) {
        acc[j] += __shfl_xor(acc[j], 16, 64);
        acc[j] += __shfl_xor(acc[j], 32, 64);
    }
    if (ss == 0) {
        uint4 o;
        o.x = f2bf(acc[0]) | ((unsigned)f2bf(acc[1]) << 16);
        o.y = f2bf(acc[2]) | ((unsigned)f2bf(acc[3]) << 16);
        o.z = f2bf(acc[4]) | ((unsigned)f2bf(acc[5]) << 16);
        o.w = f2bf(acc[6]) | ((unsigned)f2bf(acc[7]) << 16);
        aggb4[(size_t)wid * 16 + ln] = o;
    }
}

// ---------------- fused GEMM for all paths + score ----------------
// z_pn = (agg_pn @ W_p) * rsqrt(max(deg_in,1)) + b_p  ; scorep[wave] = sum tanh(z@w1+b1)@w2
__global__ __launch_bounds__(256) void gemm_all(const unsigned short* __restrict__ aggb,
                                                const unsigned short* __restrict__ Wtb,   // [3][n][k]
                                                const unsigned short* __restrict__ w1tb,  // [n][k]
                                                const int* __restrict__ cnt_in,
                                                const float* __restrict__ b_gc,
                                                const float* __restrict__ b1,
                                                const float* __restrict__ w2,
                                                float* __restrict__ z,
                                                float* __restrict__ scorep) {
    __shared__ float zS[4][16][132];
    int wave = threadIdx.x >> 6, lane = threadIdx.x & 63;
    int m = lane & 15, quad = lane >> 4;
    int r0 = blockIdx.x * 64 + wave * 16;
    if (r0 >= NROWS_ALL) return;                 // whole-wave uniform
    int p = r0 / N_NODES;                        // 16-band never crosses a path
    const short* ab = (const short*)aggb;
    bf16x8 a[4];
#pragma unroll
    for (int q = 0; q < 4; ++q)
        a[q] = *(const bf16x8*)(ab + (size_t)(r0 + m) * DIM + q * 32 + quad * 8);
    float s[4];
#pragma unroll
    for (int rg = 0; rg < 4; ++rg)
        s[rg] = rsqrtf(fmaxf((float)cnt_in[r0 + quad * 4 + rg], 1.0f));
    const short* wb = (const short*)(Wtb + (size_t)p * DIM * DIM);
    const float* bgc = b_gc + p * DIM;
    float (*zw)[132] = zS[wave];
#pragma unroll
    for (int n0 = 0; n0 < 8; ++n0) {
        f32x4 acc = {0.f, 0.f, 0.f, 0.f};
#pragma unroll
        for (int q = 0; q < 4; ++q) {
            bf16x8 b = *(const bf16x8*)(wb + (n0 * 16 + m) * DIM + q * 32 + quad * 8);
            acc = __builtin_amdgcn_mfma_f32_16x16x32_bf16(a[q], b, acc, 0, 0, 0);
        }
        int colj = n0 * 16 + m;
        float bias = bgc[colj];
#pragma unroll
        for (int rg = 0; rg < 4; ++rg)           // C/D: row=quad*4+rg, col=m
            zw[quad * 4 + rg][colj] = acc[rg] * s[rg] + bias;
    }
    // coalesced z store from LDS (per-wave slab; intra-wave LDS ops are in-order)
#pragma unroll
    for (int i = 0; i < 8; ++i) {
        int fi = i * 64 + lane;
        int row = fi >> 5, c4 = fi & 31;
        float4 v = *(const float4*)&zw[row][c4 * 4];
        *(float4*)(z + (size_t)(r0 + row) * DIM + c4 * 4) = v;
    }
    // score GEMM: rebuild A-frags from LDS
    bf16x8 sa[4];
#pragma unroll
    for (int q = 0; q < 4; ++q) {
        const float* pr = &zw[m][q * 32 + quad * 8];
        float4 f0 = *(const float4*)pr;
        float4 f1 = *(const float4*)(pr + 4);
        bf16x8 t;
        t[0] = f2bf(f0.x); t[1] = f2bf(f0.y); t[2] = f2bf(f0.z); t[3] = f2bf(f0.w);
        t[4] = f2bf(f1.x); t[5] = f2bf(f1.y); t[6] = f2bf(f1.z); t[7] = f2bf(f1.w);
        sa[q] = t;
    }
    const short* w1b = (const short*)w1tb;
    float rsum[4] = {0.f, 0.f, 0.f, 0.f};
#pragma unroll
    for (int n0 = 0; n0 < 8; ++n0) {
        f32x4 acc = {0.f, 0.f, 0.f, 0.f};
#pragma unroll
        for (int q = 0; q < 4; ++q) {
            bf16x8 b = *(const bf16x8*)(w1b + (n0 * 16 + m) * DIM + q * 32 + quad * 8);
            acc = __builtin_amdgcn_mfma_f32_16x16x32_bf16(sa[q], b, acc, 0, 0, 0);
        }
        int colj = n0 * 16 + m;
        float bj = b1[colj], wj = w2[colj];
#pragma unroll
        for (int rg = 0; rg < 4; ++rg)
            rsum[rg] += tanh_fast(acc[rg] + bj) * wj;
    }
#pragma unroll
    for (int off = 1; off < 64; off <<= 1)
#pragma unroll
        for (int rg = 0; rg < 4; ++rg) rsum[rg] += __shfl_xor(rsum[rg], off, 64);
    if (lane == 0)
        scorep[r0 >> 4] = rsum[0] + rsum[1] + rsum[2] + rsum[3];
}

// ---------------- beta = softmax( path-bucketed mean of scorep ) ----------------
__global__ __launch_bounds__(1024) void beta_kernel(const float* __restrict__ scorep,
                                                    float* __restrict__ beta) {
    __shared__ float red[3][1024];
    int t = threadIdx.x;
    float a0 = 0.f, a1 = 0.f, a2 = 0.f;
    for (int i = t; i < NWAVES_SC; i += 1024) {
        float v = scorep[i];
        int p = (i * 16) / N_NODES;
        if (p == 0) a0 += v; else if (p == 1) a1 += v; else a2 += v;
    }
    red[0][t] = a0; red[1][t] = a1; red[2][t] = a2;
    __syncthreads();
    for (int off = 512; off > 0; off >>= 1) {
        if (t < off) {
            red[0][t] += red[0][t + off];
            red[1][t] += red[1][t + off];
            red[2][t] += red[2][t + off];
        }
        __syncthreads();
    }
    if (t == 0) {
        float a = red[0][0] / (float)N_NODES;
        float b = red[1][0] / (float)N_NODES;
        float c = red[2][0] / (float)N_NODES;
        float mx = fmaxf(a, fmaxf(b, c));
        float e0 = expf(a - mx), e1 = expf(b - mx), e2 = expf(c - mx);
        float sm = e0 + e1 + e2;
        beta[0] = e0 / sm; beta[1] = e1 / sm; beta[2] = e2 / sm;
    }
}

// ---------------- out = sum_p beta[p] * z[p] ----------------
__global__ void out_kernel(const float* __restrict__ z, const float* __restrict__ beta,
                           float* __restrict__ out) {
    int i = blockIdx.x * blockDim.x + threadIdx.x;
    const int nd4 = N_NODES * DIM / 4;
    if (i < nd4) {
        float b0 = beta[0], b1 = beta[1], b2 = beta[2];
        float4 z0 = ((const float4*)z)[i];
        float4 z1 = ((const float4*)z)[nd4 + i];
        float4 z2 = ((const float4*)z)[2 * (size_t)nd4 + i];
        float4 o;
        o.x = b0 * z0.x + b1 * z1.x + b2 * z2.x;
        o.y = b0 * z0.y + b1 * z1.y + b2 * z2.y;
        o.z = b0 * z0.z + b1 * z1.z + b2 * z2.z;
        o.w = b0 * z0.w + b1 * z1.w + b2 * z2.w;
        ((float4*)out)[i] = o;
    }
}

extern "C" void kernel_launch(void* const* d_in, const int* in_sizes, int n_in,
                              void* d_out, int out_size, void* d_ws, size_t ws_size,
                              hipStream_t stream) {
    const float* h    = (const float*)d_in[0];
    const float* W_gc = (const float*)d_in[1];
    const float* b_gc = (const float*)d_in[2];
    const float* w1   = (const float*)d_in[3];
    const float* b1   = (const float*)d_in[4];
    const float* w2   = (const float*)d_in[5];
    const int* esrc   = (const int*)d_in[6];
    const int* edst   = (const int*)d_in[7];
    float* out        = (float*)d_out;

    // workspace layout (4-byte word offsets)
    int*   cnt_out = (int*)d_ws;                                // 150000
    int*   cnt_in  = cnt_out + NROWS_ALL;                       // 150000
    float* beta    = (float*)d_ws + 300004;                     // 4 (+pad)
    int*   partial = (int*)d_ws + 300032;                       // 256
    float* sc_out  = (float*)d_ws + 300288;                     // 150000 (reused as scorep)
    float* scorep  = (float*)d_ws + 300288;                     //   after gather completes
    unsigned short* Wtb  = (unsigned short*)((int*)d_ws + 450288);   // 24576 words
    unsigned short* w1tb = (unsigned short*)((int*)d_ws + 474864);   // 8192 words
    unsigned int*   aggb = (unsigned int*)((int*)d_ws + 483056);     // 9.6M words
    float* z       = (float*)d_ws + 10083056;                   // 19.2M words (fp32)
    // region overlapped by z (dead before gemm_all writes z):
    int*   cursor  = (int*)d_ws + 10083056;                     // 150000
    unsigned short* col = (unsigned short*)((int*)d_ws + 10233056);  // 900000 words
    unsigned int*   hb  = (unsigned int*)((int*)d_ws + 11133056);    // 3.2M words

    hipMemsetAsync(d_ws, 0, 300288 * sizeof(int), stream);

    conv_h<<<(N_NODES * DIM / 8 + 255) / 256, 256, 0, stream>>>(h, hb);
    conv_w<<<((N_PATHS + 1) * DIM * DIM + 255) / 256, 256, 0, stream>>>(W_gc, w1, Wtb, w1tb);

    count_kernel<<<(NE_ALL + 255) / 256, 256, 0, stream>>>(esrc, edst, cnt_out, cnt_in);
    scale_kernel<<<(NROWS_ALL + 255) / 256, 256, 0, stream>>>(cnt_out, sc_out);

    scan_pass1<<<SCAN_BLOCKS, 256, 0, stream>>>(cnt_in, partial);
    scan_pass2<<<1, 256, 0, stream>>>(partial);
    scan_pass3<<<SCAN_BLOCKS, 256, 0, stream>>>(cnt_in, partial, cursor);

    fill_kernel<<<(NE_ALL + 255) / 256, 256, 0, stream>>>(esrc, edst, cursor, col);

    gather_kernel<<<(NROWS_ALL + 3) / 4, 256, 0, stream>>>(
        cursor, col, sc_out, (const uint4*)hb, (uint4*)aggb);

    gemm_all<<<(NROWS_ALL + 63) / 64, 256, 0, stream>>>(
        (const unsigned short*)aggb, Wtb, w1tb, cnt_in, b_gc, b1, w2, z, scorep);

    beta_kernel<<<1, 1024, 0, stream>>>(scorep, beta);

    out_kernel<<<(N_NODES * DIM / 4 + 255) / 256, 256, 0, stream>>>(z, beta, out);
}

// Round 7
// 375.238 us; speedup vs baseline: 6.4375x; 1.4780x over previous
//
#include <hip/hip_runtime.h>
#include <math.h>

#define N_NODES 50000
#define N_EDGES 600000
#define N_PATHS 3
#define DIM 128
#define NROWS_ALL (N_PATHS * N_NODES)      // 150000
#define NE_ALL (N_PATHS * N_EDGES)         // 1800000
#define SCAN_BLOCKS ((NROWS_ALL + 1023) / 1024)   // 147
#define NWAVES_SC (NROWS_ALL / 16)         // 9375

// CSR-build partitioning: LDS histograms, zero global atomics
#define HB_BINS 16384                      // nodes per range (64 KB LDS)
#define HB_RANGES 4                        // ceil(50000/16384)
#define HB_CHUNKS 12
#define CHUNK_E (N_EDGES / HB_CHUNKS)      // 50000 (exact)

typedef __attribute__((ext_vector_type(8))) short bf16x8;
typedef __attribute__((ext_vector_type(4))) float f32x4;

__device__ __forceinline__ unsigned short f2bf(float f) {
    unsigned u = __float_as_uint(f);
    u += 0x7FFF + ((u >> 16) & 1);          // round-to-nearest-even
    return (unsigned short)(u >> 16);
}
__device__ __forceinline__ float tanh_fast(float x) {
    return 1.0f - 2.0f / (__expf(2.0f * x) + 1.0f);
}

// ---------------- convert h -> bf16 ----------------
__global__ void conv_h(const float* __restrict__ h, unsigned int* __restrict__ hb) {
    int i = blockIdx.x * blockDim.x + threadIdx.x;      // 8 elems per thread
    if (i >= N_NODES * DIM / 8) return;
    const float4* h4 = (const float4*)h;
    float4 a = h4[2 * i], b = h4[2 * i + 1];
    uint4 o;
    o.x = f2bf(a.x) | ((unsigned)f2bf(a.y) << 16);
    o.y = f2bf(a.z) | ((unsigned)f2bf(a.w) << 16);
    o.z = f2bf(b.x) | ((unsigned)f2bf(b.y) << 16);
    o.w = f2bf(b.z) | ((unsigned)f2bf(b.w) << 16);
    ((uint4*)hb)[i] = o;
}

// ---------------- convert + transpose weights -> bf16 [n][k] ----------------
__global__ void conv_w(const float* __restrict__ W_gc, const float* __restrict__ w1,
                       unsigned short* __restrict__ Wtb, unsigned short* __restrict__ w1tb) {
    int i = blockIdx.x * blockDim.x + threadIdx.x;
    if (i < N_PATHS * DIM * DIM) {
        int p = i / (DIM * DIM), r = i % (DIM * DIM);
        int n = r / DIM, k = r % DIM;
        Wtb[i] = f2bf(W_gc[p * DIM * DIM + k * DIM + n]);
    } else if (i < (N_PATHS + 1) * DIM * DIM) {
        int r = i - N_PATHS * DIM * DIM;
        int n = r / DIM, k = r % DIM;
        w1tb[r] = f2bf(w1[k * DIM + n]);
    }
}

// ---------------- hist: LDS histogram per (type, path, range, chunk) ----------------
// type 0: src -> pcnt_out[c][pn]; type 1: dst -> pcnt_in[c][pn]. No global atomics.
__global__ __launch_bounds__(256) void hist_kernel(const int* __restrict__ esrc,
                                                   const int* __restrict__ edst,
                                                   int* __restrict__ pcnt_out,
                                                   int* __restrict__ pcnt_in) {
    __shared__ int bins[HB_BINS];
    int tid = threadIdx.x;
    {   int4* b4 = (int4*)bins;
        for (int i = tid; i < HB_BINS / 4; i += 256) b4[i] = make_int4(0, 0, 0, 0);
    }
    int b = blockIdx.x;
    int c = b % HB_CHUNKS;
    int r = (b / HB_CHUNKS) % HB_RANGES;
    int p = (b / (HB_CHUNKS * HB_RANGES)) % N_PATHS;
    int type = b / (HB_CHUNKS * HB_RANGES * N_PATHS);
    const int* ptr = (type == 0 ? esrc : edst) + (size_t)p * N_EDGES + c * CHUNK_E;
    int r0 = r * HB_BINS;
    __syncthreads();
    const int4* p4 = (const int4*)ptr;
    for (int i = tid; i < CHUNK_E / 4; i += 256) {
        int4 v = p4[i];
        int l0 = v.x - r0; if ((unsigned)l0 < HB_BINS) atomicAdd(&bins[l0], 1);
        int l1 = v.y - r0; if ((unsigned)l1 < HB_BINS) atomicAdd(&bins[l1], 1);
        int l2 = v.z - r0; if ((unsigned)l2 < HB_BINS) atomicAdd(&bins[l2], 1);
        int l3 = v.w - r0; if ((unsigned)l3 < HB_BINS) atomicAdd(&bins[l3], 1);
    }
    __syncthreads();
    int bound = min(HB_BINS, N_NODES - r0);        // 16384,16384,16384,848 (all %4==0)
    int* dst = (type == 0 ? pcnt_out : pcnt_in) + (size_t)c * NROWS_ALL + p * N_NODES + r0;
    const int4* b4 = (const int4*)bins;
    int4* d4 = (int4*)dst;
    for (int i = tid; i < bound / 4; i += 256) d4[i] = b4[i];
}

// ---------------- merge chunk-private counts; sc_out table ----------------
__global__ void merge_kernel(const int* __restrict__ pcnt_out, const int* __restrict__ pcnt_in,
                             int* __restrict__ cnt_out, int* __restrict__ cnt_in,
                             float* __restrict__ sc_out) {
    int pn = blockIdx.x * blockDim.x + threadIdx.x;
    if (pn < NROWS_ALL) {
        int si = 0, so = 0;
#pragma unroll
        for (int c = 0; c < HB_CHUNKS; ++c) {
            si += pcnt_in [(size_t)c * NROWS_ALL + pn];
            so += pcnt_out[(size_t)c * NROWS_ALL + pn];
        }
        cnt_in[pn] = si;
        cnt_out[pn] = so;
        sc_out[pn] = rsqrtf(fmaxf((float)so, 1.0f));
    }
}

// ---------------- scan pass1: block sums of cnt_in ----------------
__global__ __launch_bounds__(256) void scan_pass1(const int* __restrict__ cnt,
                                                  int* __restrict__ partial) {
    __shared__ int lds[256];
    int t = threadIdx.x;
    int base = blockIdx.x * 1024 + t * 4;
    int4 v = make_int4(0, 0, 0, 0);
    if (base < NROWS_ALL) v = *(const int4*)(cnt + base);
    int s = v.x + v.y + v.z + v.w;
    lds[t] = s; __syncthreads();
    for (int off = 1; off < 256; off <<= 1) {
        int u = (t >= off) ? lds[t - off] : 0;
        __syncthreads();
        lds[t] += u;
        __syncthreads();
    }
    if (t == 255) partial[blockIdx.x] = lds[255];
}

// ---------------- scan pass2: exclusive scan of partials ----------------
__global__ __launch_bounds__(256) void scan_pass2(int* __restrict__ partial) {
    __shared__ int lds[256];
    int t = threadIdx.x;
    int s = (t < SCAN_BLOCKS) ? partial[t] : 0;
    lds[t] = s; __syncthreads();
    for (int off = 1; off < 256; off <<= 1) {
        int u = (t >= off) ? lds[t - off] : 0;
        __syncthreads();
        lds[t] += u;
        __syncthreads();
    }
    if (t < SCAN_BLOCKS) partial[t] = lds[t] - s;
}

// ---------------- scan pass3: write exclusive scan -> cursor (row pointers) ----------------
__global__ __launch_bounds__(256) void scan_pass3(const int* __restrict__ cnt,
                                                  const int* __restrict__ partial,
                                                  int* __restrict__ cursor) {
    __shared__ int lds[256];
    int t = threadIdx.x;
    int base = blockIdx.x * 1024 + t * 4;
    int4 v = make_int4(0, 0, 0, 0);
    if (base < NROWS_ALL) v = *(const int4*)(cnt + base);
    int s = v.x + v.y + v.z + v.w;
    lds[t] = s; __syncthreads();
    for (int off = 1; off < 256; off <<= 1) {
        int u = (t >= off) ? lds[t - off] : 0;
        __syncthreads();
        lds[t] += u;
        __syncthreads();
    }
    if (base < NROWS_ALL) {
        int run = partial[blockIdx.x] + lds[t] - s;
        int vv[4] = {v.x, v.y, v.z, v.w};
#pragma unroll
        for (int j = 0; j < 4; ++j) { cursor[base + j] = run; run += vv[j]; }
    }
}

// ---------------- chunkbase: pcnt_in[c][pn] -> write base for (chunk c, node pn) ----------------
__global__ void chunkbase_kernel(const int* __restrict__ cursor, int* __restrict__ pcnt_in) {
    int pn = blockIdx.x * blockDim.x + threadIdx.x;
    if (pn < NROWS_ALL) {
        int base = cursor[pn];
#pragma unroll
        for (int c = 0; c < HB_CHUNKS; ++c) {
            int t = pcnt_in[(size_t)c * NROWS_ALL + pn];
            pcnt_in[(size_t)c * NROWS_ALL + pn] = base;
            base += t;
        }
    }
}

// ---------------- fill2: place edges via LDS cursors (no global atomics) ----------------
__global__ __launch_bounds__(256) void fill2_kernel(const int* __restrict__ esrc,
                                                    const int* __restrict__ edst,
                                                    const int* __restrict__ pcnt_in,  // bases
                                                    unsigned short* __restrict__ col) {
    __shared__ int curs[HB_BINS];
    int tid = threadIdx.x;
    int b = blockIdx.x;
    int c = b % HB_CHUNKS;
    int r = (b / HB_CHUNKS) % HB_RANGES;
    int p = b / (HB_CHUNKS * HB_RANGES);
    int r0 = r * HB_BINS;
    int bound = min(HB_BINS, N_NODES - r0);
    const int* basep = pcnt_in + (size_t)c * NROWS_ALL + p * N_NODES + r0;
    for (int i = tid; i < bound; i += 256) curs[i] = basep[i];
    __syncthreads();
    const int4* sp4 = (const int4*)(esrc + (size_t)p * N_EDGES + c * CHUNK_E);
    const int4* dp4 = (const int4*)(edst + (size_t)p * N_EDGES + c * CHUNK_E);
    for (int i = tid; i < CHUNK_E / 4; i += 256) {
        int4 dv = dp4[i];
        int4 sv = sp4[i];
        int l0 = dv.x - r0; if ((unsigned)l0 < HB_BINS) { int pos = atomicAdd(&curs[l0], 1); col[pos] = (unsigned short)sv.x; }
        int l1 = dv.y - r0; if ((unsigned)l1 < HB_BINS) { int pos = atomicAdd(&curs[l1], 1); col[pos] = (unsigned short)sv.y; }
        int l2 = dv.z - r0; if ((unsigned)l2 < HB_BINS) { int pos = atomicAdd(&curs[l2], 1); col[pos] = (unsigned short)sv.z; }
        int l3 = dv.w - r0; if ((unsigned)l3 < HB_BINS) { int pos = atomicAdd(&curs[l3], 1); col[pos] = (unsigned short)sv.w; }
    }
}

// ---------------- gather: 4 edge-slots x 16 lanes x 8 dims ----------------
// aggb[pn] = bf16( sum_src h[src]*sc_out[src] );  beg=cursor[pn], len=cnt_in[pn]
__global__ __launch_bounds__(256) void gather_kernel(const int* __restrict__ cursor,
                                                     const int* __restrict__ cnt_in,
                                                     const unsigned short* __restrict__ col,
                                                     const float* __restrict__ sc_out,
                                                     const uint4* __restrict__ hb4,
                                                     uint4* __restrict__ aggb4) {
    int wid = blockIdx.x * 4 + (threadIdx.x >> 6);
    int lane = threadIdx.x & 63;
    int ss = lane >> 4;          // edge slot 0..3
    int ln = lane & 15;          // dim group: dims [ln*8, ln*8+8)
    if (wid >= NROWS_ALL) return;
    int p = wid / N_NODES;
    int beg = cursor[wid];
    int end = beg + cnt_in[wid];
    const float* scp = sc_out + p * N_NODES;
    float acc[8] = {};
    for (int e = beg + ss; e < end; e += 4) {
        int s = col[e];                              // uniform within slot
        float sc = scp[s];
        uint4 v = hb4[s * 16 + ln];                  // 16 B = 8 bf16 (row stride 16)
        acc[0] = fmaf(__uint_as_float(v.x << 16),        sc, acc[0]);
        acc[1] = fmaf(__uint_as_float(v.x & 0xFFFF0000u), sc, acc[1]);
        acc[2] = fmaf(__uint_as_float(v.y << 16),        sc, acc[2]);
        acc[3] = fmaf(__uint_as_float(v.y & 0xFFFF0000u), sc, acc[3]);
        acc[4] = fmaf(__uint_as_float(v.z << 16),        sc, acc[4]);
        acc[5] = fmaf(__uint_as_float(v.z & 0xFFFF0000u), sc, acc[5]);
        acc[6] = fmaf(__uint_as_float(v.w << 16),        sc, acc[6]);
        acc[7] = fmaf(__uint_as_float(v.w & 0xFFFF0000u), sc, acc[7]);
    }
#pragma unroll
    for (int j = 0; j < 8; ++j) {
        acc[j] += __shfl_xor(acc[j], 16, 64);
        acc[j] += __shfl_xor(acc[j], 32, 64);
    }
    if (ss == 0) {
        uint4 o;
        o.x = f2bf(acc[0]) | ((unsigned)f2bf(acc[1]) << 16);
        o.y = f2bf(acc[2]) | ((unsigned)f2bf(acc[3]) << 16);
        o.z = f2bf(acc[4]) | ((unsigned)f2bf(acc[5]) << 16);
        o.w = f2bf(acc[6]) | ((unsigned)f2bf(acc[7]) << 16);
        aggb4[(size_t)wid * 16 + ln] = o;
    }
}

// ---------------- fused GEMM for all paths + score ----------------
__global__ __launch_bounds__(256) void gemm_all(const unsigned short* __restrict__ aggb,
                                                const unsigned short* __restrict__ Wtb,   // [3][n][k]
                                                const unsigned short* __restrict__ w1tb,  // [n][k]
                                                const int* __restrict__ cnt_in,
                                                const float* __restrict__ b_gc,
                                                const float* __restrict__ b1,
                                                const float* __restrict__ w2,
                                                float* __restrict__ z,
                                                float* __restrict__ scorep) {
    __shared__ float zS[4][16][132];
    int wave = threadIdx.x >> 6, lane = threadIdx.x & 63;
    int m = lane & 15, quad = lane >> 4;
    int r0 = blockIdx.x * 64 + wave * 16;
    if (r0 >= NROWS_ALL) return;                 // whole-wave uniform
    int p = r0 / N_NODES;                        // 16-band never crosses a path
    const short* ab = (const short*)aggb;
    bf16x8 a[4];
#pragma unroll
    for (int q = 0; q < 4; ++q)
        a[q] = *(const bf16x8*)(ab + (size_t)(r0 + m) * DIM + q * 32 + quad * 8);
    float s[4];
#pragma unroll
    for (int rg = 0; rg < 4; ++rg)
        s[rg] = rsqrtf(fmaxf((float)cnt_in[r0 + quad * 4 + rg], 1.0f));
    const short* wb = (const short*)(Wtb + (size_t)p * DIM * DIM);
    const float* bgc = b_gc + p * DIM;
    float (*zw)[132] = zS[wave];
#pragma unroll
    for (int n0 = 0; n0 < 8; ++n0) {
        f32x4 acc = {0.f, 0.f, 0.f, 0.f};
#pragma unroll
        for (int q = 0; q < 4; ++q) {
            bf16x8 b = *(const bf16x8*)(wb + (n0 * 16 + m) * DIM + q * 32 + quad * 8);
            acc = __builtin_amdgcn_mfma_f32_16x16x32_bf16(a[q], b, acc, 0, 0, 0);
        }
        int colj = n0 * 16 + m;
        float bias = bgc[colj];
#pragma unroll
        for (int rg = 0; rg < 4; ++rg)           // C/D: row=quad*4+rg, col=m
            zw[quad * 4 + rg][colj] = acc[rg] * s[rg] + bias;
    }
    // coalesced z store from LDS (per-wave slab; intra-wave LDS ops are in-order)
#pragma unroll
    for (int i = 0; i < 8; ++i) {
        int fi = i * 64 + lane;
        int row = fi >> 5, c4 = fi & 31;
        float4 v = *(const float4*)&zw[row][c4 * 4];
        *(float4*)(z + (size_t)(r0 + row) * DIM + c4 * 4) = v;
    }
    // score GEMM: rebuild A-frags from LDS
    bf16x8 sa[4];
#pragma unroll
    for (int q = 0; q < 4; ++q) {
        const float* pr = &zw[m][q * 32 + quad * 8];
        float4 f0 = *(const float4*)pr;
        float4 f1 = *(const float4*)(pr + 4);
        bf16x8 t;
        t[0] = f2bf(f0.x); t[1] = f2bf(f0.y); t[2] = f2bf(f0.z); t[3] = f2bf(f0.w);
        t[4] = f2bf(f1.x); t[5] = f2bf(f1.y); t[6] = f2bf(f1.z); t[7] = f2bf(f1.w);
        sa[q] = t;
    }
    const short* w1b = (const short*)w1tb;
    float rsum[4] = {0.f, 0.f, 0.f, 0.f};
#pragma unroll
    for (int n0 = 0; n0 < 8; ++n0) {
        f32x4 acc = {0.f, 0.f, 0.f, 0.f};
#pragma unroll
        for (int q = 0; q < 4; ++q) {
            bf16x8 b = *(const bf16x8*)(w1b + (n0 * 16 + m) * DIM + q * 32 + quad * 8);
            acc = __builtin_amdgcn_mfma_f32_16x16x32_bf16(sa[q], b, acc, 0, 0, 0);
        }
        int colj = n0 * 16 + m;
        float bj = b1[colj], wj = w2[colj];
#pragma unroll
        for (int rg = 0; rg < 4; ++rg)
            rsum[rg] += tanh_fast(acc[rg] + bj) * wj;
    }
#pragma unroll
    for (int off = 1; off < 64; off <<= 1)
#pragma unroll
        for (int rg = 0; rg < 4; ++rg) rsum[rg] += __shfl_xor(rsum[rg], off, 64);
    if (lane == 0)
        scorep[r0 >> 4] = rsum[0] + rsum[1] + rsum[2] + rsum[3];
}

// ---------------- beta = softmax( path-bucketed mean of scorep ) ----------------
__global__ __launch_bounds__(1024) void beta_kernel(const float* __restrict__ scorep,
                                                    float* __restrict__ beta) {
    __shared__ float red[3][1024];
    int t = threadIdx.x;
    float a0 = 0.f, a1 = 0.f, a2 = 0.f;
    for (int i = t; i < NWAVES_SC; i += 1024) {
        float v = scorep[i];
        int p = (i * 16) / N_NODES;
        if (p == 0) a0 += v; else if (p == 1) a1 += v; else a2 += v;
    }
    red[0][t] = a0; red[1][t] = a1; red[2][t] = a2;
    __syncthreads();
    for (int off = 512; off > 0; off >>= 1) {
        if (t < off) {
            red[0][t] += red[0][t + off];
            red[1][t] += red[1][t + off];
            red[2][t] += red[2][t + off];
        }
        __syncthreads();
    }
    if (t == 0) {
        float a = red[0][0] / (float)N_NODES;
        float b = red[1][0] / (float)N_NODES;
        float c = red[2][0] / (float)N_NODES;
        float mx = fmaxf(a, fmaxf(b, c));
        float e0 = expf(a - mx), e1 = expf(b - mx), e2 = expf(c - mx);
        float sm = e0 + e1 + e2;
        beta[0] = e0 / sm; beta[1] = e1 / sm; beta[2] = e2 / sm;
    }
}

// ---------------- out = sum_p beta[p] * z[p] ----------------
__global__ void out_kernel(const float* __restrict__ z, const float* __restrict__ beta,
                           float* __restrict__ out) {
    int i = blockIdx.x * blockDim.x + threadIdx.x;
    const int nd4 = N_NODES * DIM / 4;
    if (i < nd4) {
        float b0 = beta[0], b1 = beta[1], b2 = beta[2];
        float4 z0 = ((const float4*)z)[i];
        float4 z1 = ((const float4*)z)[nd4 + i];
        float4 z2 = ((const float4*)z)[2 * (size_t)nd4 + i];
        float4 o;
        o.x = b0 * z0.x + b1 * z1.x + b2 * z2.x;
        o.y = b0 * z0.y + b1 * z1.y + b2 * z2.y;
        o.z = b0 * z0.z + b1 * z1.z + b2 * z2.z;
        o.w = b0 * z0.w + b1 * z1.w + b2 * z2.w;
        ((float4*)out)[i] = o;
    }
}

extern "C" void kernel_launch(void* const* d_in, const int* in_sizes, int n_in,
                              void* d_out, int out_size, void* d_ws, size_t ws_size,
                              hipStream_t stream) {
    const float* h    = (const float*)d_in[0];
    const float* W_gc = (const float*)d_in[1];
    const float* b_gc = (const float*)d_in[2];
    const float* w1   = (const float*)d_in[3];
    const float* b1   = (const float*)d_in[4];
    const float* w2   = (const float*)d_in[5];
    const int* esrc   = (const int*)d_in[6];
    const int* edst   = (const int*)d_in[7];
    float* out        = (float*)d_out;

    // workspace layout (4-byte word offsets)
    int*   cnt_out = (int*)d_ws;                                // 150000
    int*   cnt_in  = cnt_out + NROWS_ALL;                       // 150000
    float* beta    = (float*)d_ws + 300004;                     // 4 (+pad)
    int*   partial = (int*)d_ws + 300032;                       // 256
    float* sc_out  = (float*)d_ws + 300288;                     // 150000 (reused as scorep)
    float* scorep  = (float*)d_ws + 300288;                     //   after gather completes
    unsigned short* Wtb  = (unsigned short*)((int*)d_ws + 450288);   // 24576 words
    unsigned short* w1tb = (unsigned short*)((int*)d_ws + 474864);   // 8192 words
    unsigned int*   aggb = (unsigned int*)((int*)d_ws + 483056);     // 9.6M words
    float* z       = (float*)d_ws + 10083056;                   // 19.2M words (fp32)
    // overlapped by z (all dead before gemm_all writes z):
    int*   cursor  = (int*)d_ws + 10083056;                     // 150000
    unsigned short* col = (unsigned short*)((int*)d_ws + 10233056);  // 900000 words
    unsigned int*   hb  = (unsigned int*)((int*)d_ws + 11133056);    // 3.2M words
    int*   pcnt_out = (int*)d_ws + 14333056;                    // 12*150000 = 1.8M words
    int*   pcnt_in  = (int*)d_ws + 16133056;                    // 1.8M words (ends 17.93M < 29.28M)

    conv_h<<<(N_NODES * DIM / 8 + 255) / 256, 256, 0, stream>>>(h, hb);
    conv_w<<<((N_PATHS + 1) * DIM * DIM + 255) / 256, 256, 0, stream>>>(W_gc, w1, Wtb, w1tb);

    hist_kernel<<<2 * N_PATHS * HB_RANGES * HB_CHUNKS, 256, 0, stream>>>(
        esrc, edst, pcnt_out, pcnt_in);

    merge_kernel<<<(NROWS_ALL + 255) / 256, 256, 0, stream>>>(
        pcnt_out, pcnt_in, cnt_out, cnt_in, sc_out);

    scan_pass1<<<SCAN_BLOCKS, 256, 0, stream>>>(cnt_in, partial);
    scan_pass2<<<1, 256, 0, stream>>>(partial);
    scan_pass3<<<SCAN_BLOCKS, 256, 0, stream>>>(cnt_in, partial, cursor);

    chunkbase_kernel<<<(NROWS_ALL + 255) / 256, 256, 0, stream>>>(cursor, pcnt_in);

    fill2_kernel<<<N_PATHS * HB_RANGES * HB_CHUNKS, 256, 0, stream>>>(
        esrc, edst, pcnt_in, col);

    gather_kernel<<<(NROWS_ALL + 3) / 4, 256, 0, stream>>>(
        cursor, cnt_in, col, sc_out, (const uint4*)hb, (uint4*)aggb);

    gemm_all<<<(NROWS_ALL + 63) / 64, 256, 0, stream>>>(
        (const unsigned short*)aggb, Wtb, w1tb, cnt_in, b_gc, b1, w2, z, scorep);

    beta_kernel<<<1, 1024, 0, stream>>>(scorep, beta);

    out_kernel<<<(N_NODES * DIM / 4 + 255) / 256, 256, 0, stream>>>(z, beta, out);
}

// Round 8
// 322.626 us; speedup vs baseline: 7.4872x; 1.1631x over previous
//
#include <hip/hip_runtime.h>
#include <math.h>

#define N_NODES 50000
#define N_EDGES 600000
#define N_PATHS 3
#define DIM 128
#define NROWS_ALL (N_PATHS * N_NODES)      // 150000
#define NE_ALL (N_PATHS * N_EDGES)         // 1800000
#define SCAN_BLOCKS ((NROWS_ALL + 1023) / 1024)   // 147
#define NTILES_ALL (NROWS_ALL / 16)        // 9375
#define NTILES_N (N_NODES / 16)            // 3125

// CSR-build partitioning: LDS histograms, zero global atomics
#define HB_BINS 16384
#define HB_RANGES 4
#define HB_CHUNKS 12
#define CHUNK_E (N_EDGES / HB_CHUNKS)      // 50000

typedef __attribute__((ext_vector_type(8))) short bf16x8;
typedef __attribute__((ext_vector_type(4))) float f32x4;

__device__ __forceinline__ unsigned short f2bf(float f) {
    unsigned u = __float_as_uint(f);
    u += 0x7FFF + ((u >> 16) & 1);          // RNE
    return (unsigned short)(u >> 16);
}
__device__ __forceinline__ float tanh_fast(float x) {
    return 1.0f - 2.0f / (__expf(2.0f * x) + 1.0f);
}

// ---------------- convert h -> bf16 ----------------
__global__ void conv_h(const float* __restrict__ h, unsigned int* __restrict__ hb) {
    int i = blockIdx.x * blockDim.x + threadIdx.x;
    if (i >= N_NODES * DIM / 8) return;
    const float4* h4 = (const float4*)h;
    float4 a = h4[2 * i], b = h4[2 * i + 1];
    uint4 o;
    o.x = f2bf(a.x) | ((unsigned)f2bf(a.y) << 16);
    o.y = f2bf(a.z) | ((unsigned)f2bf(a.w) << 16);
    o.z = f2bf(b.x) | ((unsigned)f2bf(b.y) << 16);
    o.w = f2bf(b.z) | ((unsigned)f2bf(b.w) << 16);
    ((uint4*)hb)[i] = o;
}

// ---------------- weights -> bf16 in MFMA fragment-major layout ----------------
// frag (n0,q), lane = quad*16+m holds B[k=q*32+quad*8 .. +8][n=n0*16+m]
// flat: ((mat*32 + n0*4+q)*64 + lane) * 8 shorts.  mat 0..2 = W_gc paths, 3 = w1.
__global__ void conv_w(const float* __restrict__ W_gc, const float* __restrict__ w1,
                       uint4* __restrict__ wsw) {
    int i = blockIdx.x * blockDim.x + threadIdx.x;
    if (i >= (N_PATHS + 1) * 2048) return;
    int mat = i >> 11;
    int rem = i & 2047;
    int frag = rem >> 6, lane = rem & 63;
    int n0 = frag >> 2, q = frag & 3;
    int quad = lane >> 4, m = lane & 15;
    int n = n0 * 16 + m;
    int kbase = q * 32 + quad * 8;
    const float* src = (mat < N_PATHS) ? (W_gc + (size_t)mat * DIM * DIM) : w1;
    unsigned short t[8];
#pragma unroll
    for (int j = 0; j < 8; ++j) t[j] = f2bf(src[(size_t)(kbase + j) * DIM + n]);
    uint4 o;
    o.x = t[0] | ((unsigned)t[1] << 16);
    o.y = t[2] | ((unsigned)t[3] << 16);
    o.z = t[4] | ((unsigned)t[5] << 16);
    o.w = t[6] | ((unsigned)t[7] << 16);
    wsw[i] = o;
}

// ---------------- hist: LDS histogram per (type, path, range, chunk) ----------------
__global__ __launch_bounds__(256) void hist_kernel(const int* __restrict__ esrc,
                                                   const int* __restrict__ edst,
                                                   int* __restrict__ pcnt_out,
                                                   int* __restrict__ pcnt_in) {
    __shared__ int bins[HB_BINS];
    int tid = threadIdx.x;
    {   int4* b4 = (int4*)bins;
        for (int i = tid; i < HB_BINS / 4; i += 256) b4[i] = make_int4(0, 0, 0, 0);
    }
    int b = blockIdx.x;
    int c = b % HB_CHUNKS;
    int r = (b / HB_CHUNKS) % HB_RANGES;
    int p = (b / (HB_CHUNKS * HB_RANGES)) % N_PATHS;
    int type = b / (HB_CHUNKS * HB_RANGES * N_PATHS);
    const int* ptr = (type == 0 ? esrc : edst) + (size_t)p * N_EDGES + c * CHUNK_E;
    int r0 = r * HB_BINS;
    __syncthreads();
    const int4* p4 = (const int4*)ptr;
    for (int i = tid; i < CHUNK_E / 4; i += 256) {
        int4 v = p4[i];
        int l0 = v.x - r0; if ((unsigned)l0 < HB_BINS) atomicAdd(&bins[l0], 1);
        int l1 = v.y - r0; if ((unsigned)l1 < HB_BINS) atomicAdd(&bins[l1], 1);
        int l2 = v.z - r0; if ((unsigned)l2 < HB_BINS) atomicAdd(&bins[l2], 1);
        int l3 = v.w - r0; if ((unsigned)l3 < HB_BINS) atomicAdd(&bins[l3], 1);
    }
    __syncthreads();
    int bound = min(HB_BINS, N_NODES - r0);
    int* dst = (type == 0 ? pcnt_out : pcnt_in) + (size_t)c * NROWS_ALL + p * N_NODES + r0;
    const int4* b4 = (const int4*)bins;
    int4* d4 = (int4*)dst;
    for (int i = tid; i < bound / 4; i += 256) d4[i] = b4[i];
}

// ---------------- merge chunk-private counts; sc_out table ----------------
__global__ void merge_kernel(const int* __restrict__ pcnt_out, const int* __restrict__ pcnt_in,
                             int* __restrict__ cnt_out, int* __restrict__ cnt_in,
                             float* __restrict__ sc_out) {
    int pn = blockIdx.x * blockDim.x + threadIdx.x;
    if (pn < NROWS_ALL) {
        int si = 0, so = 0;
#pragma unroll
        for (int c = 0; c < HB_CHUNKS; ++c) {
            si += pcnt_in [(size_t)c * NROWS_ALL + pn];
            so += pcnt_out[(size_t)c * NROWS_ALL + pn];
        }
        cnt_in[pn] = si;
        cnt_out[pn] = so;
        sc_out[pn] = rsqrtf(fmaxf((float)so, 1.0f));
    }
}

// ---------------- scan passes ----------------
__global__ __launch_bounds__(256) void scan_pass1(const int* __restrict__ cnt,
                                                  int* __restrict__ partial) {
    __shared__ int lds[256];
    int t = threadIdx.x;
    int base = blockIdx.x * 1024 + t * 4;
    int4 v = make_int4(0, 0, 0, 0);
    if (base < NROWS_ALL) v = *(const int4*)(cnt + base);
    int s = v.x + v.y + v.z + v.w;
    lds[t] = s; __syncthreads();
    for (int off = 1; off < 256; off <<= 1) {
        int u = (t >= off) ? lds[t - off] : 0;
        __syncthreads();
        lds[t] += u;
        __syncthreads();
    }
    if (t == 255) partial[blockIdx.x] = lds[255];
}

__global__ __launch_bounds__(256) void scan_pass2(int* __restrict__ partial) {
    __shared__ int lds[256];
    int t = threadIdx.x;
    int s = (t < SCAN_BLOCKS) ? partial[t] : 0;
    lds[t] = s; __syncthreads();
    for (int off = 1; off < 256; off <<= 1) {
        int u = (t >= off) ? lds[t - off] : 0;
        __syncthreads();
        lds[t] += u;
        __syncthreads();
    }
    if (t < SCAN_BLOCKS) partial[t] = lds[t] - s;
}

__global__ __launch_bounds__(256) void scan_pass3(const int* __restrict__ cnt,
                                                  const int* __restrict__ partial,
                                                  int* __restrict__ cursor) {
    __shared__ int lds[256];
    int t = threadIdx.x;
    int base = blockIdx.x * 1024 + t * 4;
    int4 v = make_int4(0, 0, 0, 0);
    if (base < NROWS_ALL) v = *(const int4*)(cnt + base);
    int s = v.x + v.y + v.z + v.w;
    lds[t] = s; __syncthreads();
    for (int off = 1; off < 256; off <<= 1) {
        int u = (t >= off) ? lds[t - off] : 0;
        __syncthreads();
        lds[t] += u;
        __syncthreads();
    }
    if (base < NROWS_ALL) {
        int run = partial[blockIdx.x] + lds[t] - s;
        int vv[4] = {v.x, v.y, v.z, v.w};
#pragma unroll
        for (int j = 0; j < 4; ++j) { cursor[base + j] = run; run += vv[j]; }
    }
}

// ---------------- chunkbase ----------------
__global__ void chunkbase_kernel(const int* __restrict__ cursor, int* __restrict__ pcnt_in) {
    int pn = blockIdx.x * blockDim.x + threadIdx.x;
    if (pn < NROWS_ALL) {
        int base = cursor[pn];
#pragma unroll
        for (int c = 0; c < HB_CHUNKS; ++c) {
            int t = pcnt_in[(size_t)c * NROWS_ALL + pn];
            pcnt_in[(size_t)c * NROWS_ALL + pn] = base;
            base += t;
        }
    }
}

// ---------------- fill2: place edges via LDS cursors ----------------
__global__ __launch_bounds__(256) void fill2_kernel(const int* __restrict__ esrc,
                                                    const int* __restrict__ edst,
                                                    const int* __restrict__ pcnt_in,
                                                    unsigned short* __restrict__ col) {
    __shared__ int curs[HB_BINS];
    int tid = threadIdx.x;
    int b = blockIdx.x;
    int c = b % HB_CHUNKS;
    int r = (b / HB_CHUNKS) % HB_RANGES;
    int p = b / (HB_CHUNKS * HB_RANGES);
    int r0 = r * HB_BINS;
    int bound = min(HB_BINS, N_NODES - r0);
    const int* basep = pcnt_in + (size_t)c * NROWS_ALL + p * N_NODES + r0;
    for (int i = tid; i < bound; i += 256) curs[i] = basep[i];
    __syncthreads();
    const int4* sp4 = (const int4*)(esrc + (size_t)p * N_EDGES + c * CHUNK_E);
    const int4* dp4 = (const int4*)(edst + (size_t)p * N_EDGES + c * CHUNK_E);
    for (int i = tid; i < CHUNK_E / 4; i += 256) {
        int4 dv = dp4[i];
        int4 sv = sp4[i];
        int l0 = dv.x - r0; if ((unsigned)l0 < HB_BINS) { int pos = atomicAdd(&curs[l0], 1); col[pos] = (unsigned short)sv.x; }
        int l1 = dv.y - r0; if ((unsigned)l1 < HB_BINS) { int pos = atomicAdd(&curs[l1], 1); col[pos] = (unsigned short)sv.y; }
        int l2 = dv.z - r0; if ((unsigned)l2 < HB_BINS) { int pos = atomicAdd(&curs[l2], 1); col[pos] = (unsigned short)sv.z; }
        int l3 = dv.w - r0; if ((unsigned)l3 < HB_BINS) { int pos = atomicAdd(&curs[l3], 1); col[pos] = (unsigned short)sv.w; }
    }
}

// ---------------- gather: 4 edge-slots x 16 lanes x 8 dims; frag-major agg output ----------------
// aggb4[t*256 + q*64 + quad*16 + m] = 8 bf16 of agg[t*16+m][q*32+quad*8 ..]
__global__ __launch_bounds__(256) void gather_kernel(const int* __restrict__ cursor,
                                                     const int* __restrict__ cnt_in,
                                                     const unsigned short* __restrict__ col,
                                                     const float* __restrict__ sc_out,
                                                     const uint4* __restrict__ hb4,
                                                     uint4* __restrict__ aggb4) {
    int wid = blockIdx.x * 4 + (threadIdx.x >> 6);
    int lane = threadIdx.x & 63;
    int ss = lane >> 4;
    int ln = lane & 15;
    if (wid >= NROWS_ALL) return;
    int p = wid / N_NODES;
    int beg = cursor[wid];
    int end = beg + cnt_in[wid];
    const float* scp = sc_out + p * N_NODES;
    float acc[8] = {};
    for (int e = beg + ss; e < end; e += 4) {
        int s = col[e];
        float sc = scp[s];
        uint4 v = hb4[s * 16 + ln];
        acc[0] = fmaf(__uint_as_float(v.x << 16),        sc, acc[0]);
        acc[1] = fmaf(__uint_as_float(v.x & 0xFFFF0000u), sc, acc[1]);
        acc[2] = fmaf(__uint_as_float(v.y << 16),        sc, acc[2]);
        acc[3] = fmaf(__uint_as_float(v.y & 0xFFFF0000u), sc, acc[3]);
        acc[4] = fmaf(__uint_as_float(v.z << 16),        sc, acc[4]);
        acc[5] = fmaf(__uint_as_float(v.z & 0xFFFF0000u), sc, acc[5]);
        acc[6] = fmaf(__uint_as_float(v.w << 16),        sc, acc[6]);
        acc[7] = fmaf(__uint_as_float(v.w & 0xFFFF0000u), sc, acc[7]);
    }
#pragma unroll
    for (int j = 0; j < 8; ++j) {
        acc[j] += __shfl_xor(acc[j], 16, 64);
        acc[j] += __shfl_xor(acc[j], 32, 64);
    }
    if (ss == 0) {
        uint4 o;
        o.x = f2bf(acc[0]) | ((unsigned)f2bf(acc[1]) << 16);
        o.y = f2bf(acc[2]) | ((unsigned)f2bf(acc[3]) << 16);
        o.z = f2bf(acc[4]) | ((unsigned)f2bf(acc[5]) << 16);
        o.w = f2bf(acc[6]) | ((unsigned)f2bf(acc[7]) << 16);
        int t = wid >> 4, m = wid & 15, q = ln >> 2, qd = ln & 3;
        aggb4[(size_t)t * 256 + q * 64 + qd * 16 + m] = o;
    }
}

// ---------------- score pass: gemm1 -> LDS transpose -> gemm2 -> tanh -> score ----------------
__global__ __launch_bounds__(256, 4) void score_pass(const uint4* __restrict__ aggb4,
                                                     const uint4* __restrict__ wsw,
                                                     const int* __restrict__ cnt_in,
                                                     const float* __restrict__ b_gc,
                                                     const float* __restrict__ b1,
                                                     const float* __restrict__ w2,
                                                     float* __restrict__ scorep) {
    __shared__ float zS[4][16][132];
    int wave = threadIdx.x >> 6, lane = threadIdx.x & 63;
    int m = lane & 15, quad = lane >> 4;
    int t = blockIdx.x * 4 + wave;
    if (t >= NTILES_ALL) return;
    int r0 = t * 16;
    int p = r0 / N_NODES;
    const uint4* At = aggb4 + (size_t)t * 256 + lane;
    bf16x8 a[4];
#pragma unroll
    for (int q = 0; q < 4; ++q) a[q] = *(const bf16x8*)&At[q * 64];
    float s[4];
#pragma unroll
    for (int rg = 0; rg < 4; ++rg)
        s[rg] = rsqrtf(fmaxf((float)cnt_in[r0 + quad * 4 + rg], 1.0f));
    const uint4* Bp = wsw + (size_t)p * 2048 + lane;
    const float* bgc = b_gc + p * DIM;
    float (*zw)[132] = zS[wave];
#pragma unroll
    for (int n0 = 0; n0 < 8; ++n0) {
        f32x4 acc = {0.f, 0.f, 0.f, 0.f};
#pragma unroll
        for (int q = 0; q < 4; ++q) {
            bf16x8 b = *(const bf16x8*)&Bp[(n0 * 4 + q) * 64];
            acc = __builtin_amdgcn_mfma_f32_16x16x32_bf16(a[q], b, acc, 0, 0, 0);
        }
        int colj = n0 * 16 + m;
        float bias = bgc[colj];
#pragma unroll
        for (int rg = 0; rg < 4; ++rg)
            zw[quad * 4 + rg][colj] = acc[rg] * s[rg] + bias;
    }
    // transpose read (intra-wave LDS, in-order)
    bf16x8 sa[4];
#pragma unroll
    for (int q = 0; q < 4; ++q) {
        const float* pr = &zw[m][q * 32 + quad * 8];
        float4 f0 = *(const float4*)pr;
        float4 f1 = *(const float4*)(pr + 4);
        bf16x8 tt;
        tt[0] = f2bf(f0.x); tt[1] = f2bf(f0.y); tt[2] = f2bf(f0.z); tt[3] = f2bf(f0.w);
        tt[4] = f2bf(f1.x); tt[5] = f2bf(f1.y); tt[6] = f2bf(f1.z); tt[7] = f2bf(f1.w);
        sa[q] = tt;
    }
    const uint4* W1 = wsw + (size_t)N_PATHS * 2048 + lane;
    float rsum[4] = {0.f, 0.f, 0.f, 0.f};
#pragma unroll
    for (int n0 = 0; n0 < 8; ++n0) {
        f32x4 acc = {0.f, 0.f, 0.f, 0.f};
#pragma unroll
        for (int q = 0; q < 4; ++q) {
            bf16x8 b = *(const bf16x8*)&W1[(n0 * 4 + q) * 64];
            acc = __builtin_amdgcn_mfma_f32_16x16x32_bf16(sa[q], b, acc, 0, 0, 0);
        }
        int colj = n0 * 16 + m;
        float bj = b1[colj], wj = w2[colj];
#pragma unroll
        for (int rg = 0; rg < 4; ++rg)
            rsum[rg] += tanh_fast(acc[rg] + bj) * wj;
    }
#pragma unroll
    for (int off = 1; off < 64; off <<= 1)
#pragma unroll
        for (int rg = 0; rg < 4; ++rg) rsum[rg] += __shfl_xor(rsum[rg], off, 64);
    if (lane == 0)
        scorep[t] = rsum[0] + rsum[1] + rsum[2] + rsum[3];
}

// ---------------- beta = softmax( path-bucketed mean of scorep ) ----------------
__global__ __launch_bounds__(1024) void beta_kernel(const float* __restrict__ scorep,
                                                    float* __restrict__ beta) {
    __shared__ float red[3][1024];
    int t = threadIdx.x;
    float a0 = 0.f, a1 = 0.f, a2 = 0.f;
    for (int i = t; i < NTILES_ALL; i += 1024) {
        float v = scorep[i];
        int p = (i * 16) / N_NODES;
        if (p == 0) a0 += v; else if (p == 1) a1 += v; else a2 += v;
    }
    red[0][t] = a0; red[1][t] = a1; red[2][t] = a2;
    __syncthreads();
    for (int off = 512; off > 0; off >>= 1) {
        if (t < off) {
            red[0][t] += red[0][t + off];
            red[1][t] += red[1][t + off];
            red[2][t] += red[2][t + off];
        }
        __syncthreads();
    }
    if (t == 0) {
        float a = red[0][0] / (float)N_NODES;
        float b = red[1][0] / (float)N_NODES;
        float c = red[2][0] / (float)N_NODES;
        float mx = fmaxf(a, fmaxf(b, c));
        float e0 = expf(a - mx), e1 = expf(b - mx), e2 = expf(c - mx);
        float sm = e0 + e1 + e2;
        beta[0] = e0 / sm; beta[1] = e1 / sm; beta[2] = e2 / sm;
    }
}

// ---------------- out pass: out = sum_p beta_p * ((agg_p @ W_p)*s + b_p) ----------------
__global__ __launch_bounds__(256, 4) void out_pass(const uint4* __restrict__ aggb4,
                                                   const uint4* __restrict__ wsw,
                                                   const int* __restrict__ cnt_in,
                                                   const float* __restrict__ b_gc,
                                                   const float* __restrict__ beta,
                                                   float* __restrict__ out) {
    __shared__ float zS[4][16][132];
    int wave = threadIdx.x >> 6, lane = threadIdx.x & 63;
    int m = lane & 15, quad = lane >> 4;
    int t = blockIdx.x * 4 + wave;
    if (t >= NTILES_N) return;
    int r0 = t * 16;
    float of[8][4] = {};
#pragma unroll
    for (int p = 0; p < N_PATHS; ++p) {
        const uint4* At = aggb4 + (size_t)(p * NTILES_N + t) * 256 + lane;
        bf16x8 a[4];
#pragma unroll
        for (int q = 0; q < 4; ++q) a[q] = *(const bf16x8*)&At[q * 64];
        float s[4];
#pragma unroll
        for (int rg = 0; rg < 4; ++rg)
            s[rg] = rsqrtf(fmaxf((float)cnt_in[p * N_NODES + r0 + quad * 4 + rg], 1.0f));
        float bp = beta[p];
        const uint4* Bp = wsw + (size_t)p * 2048 + lane;
        const float* bgc = b_gc + p * DIM;
#pragma unroll
        for (int n0 = 0; n0 < 8; ++n0) {
            f32x4 acc = {0.f, 0.f, 0.f, 0.f};
#pragma unroll
            for (int q = 0; q < 4; ++q) {
                bf16x8 b = *(const bf16x8*)&Bp[(n0 * 4 + q) * 64];
                acc = __builtin_amdgcn_mfma_f32_16x16x32_bf16(a[q], b, acc, 0, 0, 0);
            }
            float bias = bgc[n0 * 16 + m];
#pragma unroll
            for (int rg = 0; rg < 4; ++rg)
                of[n0][rg] = fmaf(bp, acc[rg] * s[rg] + bias, of[n0][rg]);
        }
    }
    float (*zw)[132] = zS[wave];
#pragma unroll
    for (int n0 = 0; n0 < 8; ++n0)
#pragma unroll
        for (int rg = 0; rg < 4; ++rg)
            zw[quad * 4 + rg][n0 * 16 + m] = of[n0][rg];
#pragma unroll
    for (int i = 0; i < 8; ++i) {
        int fi = i * 64 + lane;
        int row = fi >> 5, c4 = fi & 31;
        float4 v = *(const float4*)&zw[row][c4 * 4];
        *(float4*)(out + (size_t)(r0 + row) * DIM + c4 * 4) = v;
    }
}

extern "C" void kernel_launch(void* const* d_in, const int* in_sizes, int n_in,
                              void* d_out, int out_size, void* d_ws, size_t ws_size,
                              hipStream_t stream) {
    const float* h    = (const float*)d_in[0];
    const float* W_gc = (const float*)d_in[1];
    const float* b_gc = (const float*)d_in[2];
    const float* w1   = (const float*)d_in[3];
    const float* b1   = (const float*)d_in[4];
    const float* w2   = (const float*)d_in[5];
    const int* esrc   = (const int*)d_in[6];
    const int* edst   = (const int*)d_in[7];
    float* out        = (float*)d_out;

    // workspace layout (4-byte word offsets)
    int*   cnt_out = (int*)d_ws;                                // 150000
    int*   cnt_in  = cnt_out + NROWS_ALL;                       // 150000
    float* beta    = (float*)d_ws + 300004;                     // 4 (+pad)
    int*   partial = (int*)d_ws + 300032;                       // 256
    float* sc_out  = (float*)d_ws + 300288;                     // 150000 (reused as scorep)
    float* scorep  = (float*)d_ws + 300288;                     //   after gather completes
    uint4* wsw     = (uint4*)((int*)d_ws + 450288);             // 4*2048 uint4 = 32768 words
    unsigned int* aggb = (unsigned int*)((int*)d_ws + 483056);  // 9.6M words
    int*   cursor  = (int*)d_ws + 10083056;                     // 150000
    unsigned short* col = (unsigned short*)((int*)d_ws + 10233056);  // 900000 words
    unsigned int*   hb  = (unsigned int*)((int*)d_ws + 11133056);    // 3.2M words
    int*   pcnt_out = (int*)d_ws + 14333056;                    // 1.8M words
    int*   pcnt_in  = (int*)d_ws + 16133056;                    // 1.8M words

    conv_h<<<(N_NODES * DIM / 8 + 255) / 256, 256, 0, stream>>>(h, hb);
    conv_w<<<((N_PATHS + 1) * 2048 + 255) / 256, 256, 0, stream>>>(W_gc, w1, wsw);

    hist_kernel<<<2 * N_PATHS * HB_RANGES * HB_CHUNKS, 256, 0, stream>>>(
        esrc, edst, pcnt_out, pcnt_in);

    merge_kernel<<<(NROWS_ALL + 255) / 256, 256, 0, stream>>>(
        pcnt_out, pcnt_in, cnt_out, cnt_in, sc_out);

    scan_pass1<<<SCAN_BLOCKS, 256, 0, stream>>>(cnt_in, partial);
    scan_pass2<<<1, 256, 0, stream>>>(partial);
    scan_pass3<<<SCAN_BLOCKS, 256, 0, stream>>>(cnt_in, partial, cursor);

    chunkbase_kernel<<<(NROWS_ALL + 255) / 256, 256, 0, stream>>>(cursor, pcnt_in);

    fill2_kernel<<<N_PATHS * HB_RANGES * HB_CHUNKS, 256, 0, stream>>>(
        esrc, edst, pcnt_in, col);

    gather_kernel<<<(NROWS_ALL + 3) / 4, 256, 0, stream>>>(
        cursor, cnt_in, col, sc_out, (const uint4*)hb, (uint4*)aggb);

    score_pass<<<(NTILES_ALL + 3) / 4, 256, 0, stream>>>(
        (const uint4*)aggb, wsw, cnt_in, b_gc, b1, w2, scorep);

    beta_kernel<<<1, 1024, 0, stream>>>(scorep, beta);

    out_pass<<<(NTILES_N + 3) / 4, 256, 0, stream>>>(
        (const uint4*)aggb, wsw, cnt_in, b_gc, beta, out);
}

// Round 9
// 280.682 us; speedup vs baseline: 8.6061x; 1.1494x over previous
//
#include <hip/hip_runtime.h>
#include <math.h>

#define N_NODES 50000
#define N_EDGES 600000
#define N_PATHS 3
#define DIM 128
#define NROWS_ALL (N_PATHS * N_NODES)      // 150000
#define NE_ALL (N_PATHS * N_EDGES)         // 1800000
#define SCAN_BLOCKS ((NROWS_ALL + 1023) / 1024)   // 147
#define NTILES_ALL (NROWS_ALL / 16)        // 9375
#define NTILES_N (N_NODES / 16)            // 3125

// CSR-build partitioning: LDS histograms, zero global atomics
#define HB_BINS 16384
#define HB_RANGES 4
#define HB_CHUNKS 24
#define CHUNK_E (N_EDGES / HB_CHUNKS)      // 25000

typedef __attribute__((ext_vector_type(8))) short bf16x8;
typedef __attribute__((ext_vector_type(4))) float f32x4;

__device__ __forceinline__ unsigned short f2bf(float f) {
    unsigned u = __float_as_uint(f);
    u += 0x7FFF + ((u >> 16) & 1);          // RNE
    return (unsigned short)(u >> 16);
}
__device__ __forceinline__ float tanh_fast(float x) {
    return 1.0f - 2.0f / (__expf(2.0f * x) + 1.0f);
}

// ---------------- convert h -> bf16 ----------------
__global__ void conv_h(const float* __restrict__ h, unsigned int* __restrict__ hb) {
    int i = blockIdx.x * blockDim.x + threadIdx.x;
    if (i >= N_NODES * DIM / 8) return;
    const float4* h4 = (const float4*)h;
    float4 a = h4[2 * i], b = h4[2 * i + 1];
    uint4 o;
    o.x = f2bf(a.x) | ((unsigned)f2bf(a.y) << 16);
    o.y = f2bf(a.z) | ((unsigned)f2bf(a.w) << 16);
    o.z = f2bf(b.x) | ((unsigned)f2bf(b.y) << 16);
    o.w = f2bf(b.z) | ((unsigned)f2bf(b.w) << 16);
    ((uint4*)hb)[i] = o;
}

// ---------------- weights -> bf16 in MFMA fragment-major layout ----------------
__global__ void conv_w(const float* __restrict__ W_gc, const float* __restrict__ w1,
                       uint4* __restrict__ wsw) {
    int i = blockIdx.x * blockDim.x + threadIdx.x;
    if (i >= (N_PATHS + 1) * 2048) return;
    int mat = i >> 11;
    int rem = i & 2047;
    int frag = rem >> 6, lane = rem & 63;
    int n0 = frag >> 2, q = frag & 3;
    int quad = lane >> 4, m = lane & 15;
    int n = n0 * 16 + m;
    int kbase = q * 32 + quad * 8;
    const float* src = (mat < N_PATHS) ? (W_gc + (size_t)mat * DIM * DIM) : w1;
    unsigned short t[8];
#pragma unroll
    for (int j = 0; j < 8; ++j) t[j] = f2bf(src[(size_t)(kbase + j) * DIM + n]);
    uint4 o;
    o.x = t[0] | ((unsigned)t[1] << 16);
    o.y = t[2] | ((unsigned)t[3] << 16);
    o.z = t[4] | ((unsigned)t[5] << 16);
    o.w = t[6] | ((unsigned)t[7] << 16);
    wsw[i] = o;
}

// ---------------- hist: LDS histogram per (type, path, range, chunk), unrolled x2 ----------------
__global__ __launch_bounds__(256) void hist_kernel(const int* __restrict__ esrc,
                                                   const int* __restrict__ edst,
                                                   int* __restrict__ pcnt_out,
                                                   int* __restrict__ pcnt_in) {
    __shared__ int bins[HB_BINS];
    int tid = threadIdx.x;
    {   int4* b4 = (int4*)bins;
        for (int i = tid; i < HB_BINS / 4; i += 256) b4[i] = make_int4(0, 0, 0, 0);
    }
    int b = blockIdx.x;
    int c = b % HB_CHUNKS;
    int r = (b / HB_CHUNKS) % HB_RANGES;
    int p = (b / (HB_CHUNKS * HB_RANGES)) % N_PATHS;
    int type = b / (HB_CHUNKS * HB_RANGES * N_PATHS);
    const int* ptr = (type == 0 ? esrc : edst) + (size_t)p * N_EDGES + c * CHUNK_E;
    int r0 = r * HB_BINS;
    __syncthreads();
    const int4* p4 = (const int4*)ptr;
    // CHUNK_E/4 = 6250; even i < 6250 always has i+1 <= 6249 valid
    for (int i = tid * 2; i < CHUNK_E / 4; i += 512) {
        int4 a = p4[i];
        int4 bb = p4[i + 1];
        int l0 = a.x - r0;  if ((unsigned)l0 < HB_BINS) atomicAdd(&bins[l0], 1);
        int l1 = a.y - r0;  if ((unsigned)l1 < HB_BINS) atomicAdd(&bins[l1], 1);
        int l2 = a.z - r0;  if ((unsigned)l2 < HB_BINS) atomicAdd(&bins[l2], 1);
        int l3 = a.w - r0;  if ((unsigned)l3 < HB_BINS) atomicAdd(&bins[l3], 1);
        int l4 = bb.x - r0; if ((unsigned)l4 < HB_BINS) atomicAdd(&bins[l4], 1);
        int l5 = bb.y - r0; if ((unsigned)l5 < HB_BINS) atomicAdd(&bins[l5], 1);
        int l6 = bb.z - r0; if ((unsigned)l6 < HB_BINS) atomicAdd(&bins[l6], 1);
        int l7 = bb.w - r0; if ((unsigned)l7 < HB_BINS) atomicAdd(&bins[l7], 1);
    }
    __syncthreads();
    int bound = min(HB_BINS, N_NODES - r0);
    int* dst = (type == 0 ? pcnt_out : pcnt_in) + (size_t)c * NROWS_ALL + p * N_NODES + r0;
    const int4* b4 = (const int4*)bins;
    int4* d4 = (int4*)dst;
    for (int i = tid; i < bound / 4; i += 256) d4[i] = b4[i];
}

// ---------------- scan pass1 (fused merge): sum chunk-privates -> cnt/sc_out, block sums ----------------
__global__ __launch_bounds__(256) void scan_pass1(const int* __restrict__ pcnt_out,
                                                  const int* __restrict__ pcnt_in,
                                                  int* __restrict__ cnt_out,
                                                  int* __restrict__ cnt_in,
                                                  float* __restrict__ sc_out,
                                                  int* __restrict__ partial) {
    __shared__ int lds[256];
    int t = threadIdx.x;
    int base = blockIdx.x * 1024 + t * 4;
    int4 ci = make_int4(0, 0, 0, 0);
    if (base < NROWS_ALL) {
        int4 co = make_int4(0, 0, 0, 0);
#pragma unroll
        for (int c = 0; c < HB_CHUNKS; ++c) {
            int4 vi = *(const int4*)(pcnt_in + (size_t)c * NROWS_ALL + base);
            int4 vo = *(const int4*)(pcnt_out + (size_t)c * NROWS_ALL + base);
            ci.x += vi.x; ci.y += vi.y; ci.z += vi.z; ci.w += vi.w;
            co.x += vo.x; co.y += vo.y; co.z += vo.z; co.w += vo.w;
        }
        *(int4*)(cnt_in + base) = ci;
        *(int4*)(cnt_out + base) = co;
        float4 sc;
        sc.x = rsqrtf(fmaxf((float)co.x, 1.0f));
        sc.y = rsqrtf(fmaxf((float)co.y, 1.0f));
        sc.z = rsqrtf(fmaxf((float)co.z, 1.0f));
        sc.w = rsqrtf(fmaxf((float)co.w, 1.0f));
        *(float4*)(sc_out + base) = sc;
    }
    int s = ci.x + ci.y + ci.z + ci.w;
    lds[t] = s; __syncthreads();
    for (int off = 1; off < 256; off <<= 1) {
        int u = (t >= off) ? lds[t - off] : 0;
        __syncthreads();
        lds[t] += u;
        __syncthreads();
    }
    if (t == 255) partial[blockIdx.x] = lds[255];
}

__global__ __launch_bounds__(256) void scan_pass2(int* __restrict__ partial) {
    __shared__ int lds[256];
    int t = threadIdx.x;
    int s = (t < SCAN_BLOCKS) ? partial[t] : 0;
    lds[t] = s; __syncthreads();
    for (int off = 1; off < 256; off <<= 1) {
        int u = (t >= off) ? lds[t - off] : 0;
        __syncthreads();
        lds[t] += u;
        __syncthreads();
    }
    if (t < SCAN_BLOCKS) partial[t] = lds[t] - s;
}

// ---------------- scan pass3 (fused chunkbase): cursor + per-chunk write bases ----------------
__global__ __launch_bounds__(256) void scan_pass3(const int* __restrict__ cnt,
                                                  const int* __restrict__ partial,
                                                  int* __restrict__ cursor,
                                                  int* __restrict__ pcnt_in) {
    __shared__ int lds[256];
    int t = threadIdx.x;
    int base = blockIdx.x * 1024 + t * 4;
    int4 v = make_int4(0, 0, 0, 0);
    if (base < NROWS_ALL) v = *(const int4*)(cnt + base);
    int s = v.x + v.y + v.z + v.w;
    lds[t] = s; __syncthreads();
    for (int off = 1; off < 256; off <<= 1) {
        int u = (t >= off) ? lds[t - off] : 0;
        __syncthreads();
        lds[t] += u;
        __syncthreads();
    }
    if (base < NROWS_ALL) {
        int run = partial[blockIdx.x] + lds[t] - s;
        int vv[4] = {v.x, v.y, v.z, v.w};
        int rb[4];
#pragma unroll
        for (int j = 0; j < 4; ++j) { cursor[base + j] = run; rb[j] = run; run += vv[j]; }
        // chunk bases in-place
#pragma unroll
        for (int c = 0; c < HB_CHUNKS; ++c) {
            int4 pc = *(const int4*)(pcnt_in + (size_t)c * NROWS_ALL + base);
            *(int4*)(pcnt_in + (size_t)c * NROWS_ALL + base) = make_int4(rb[0], rb[1], rb[2], rb[3]);
            rb[0] += pc.x; rb[1] += pc.y; rb[2] += pc.z; rb[3] += pc.w;
        }
    }
}

// ---------------- fill2: place edges via LDS cursors, unrolled x2 ----------------
__global__ __launch_bounds__(256) void fill2_kernel(const int* __restrict__ esrc,
                                                    const int* __restrict__ edst,
                                                    const int* __restrict__ pcnt_in,
                                                    unsigned short* __restrict__ col) {
    __shared__ int curs[HB_BINS];
    int tid = threadIdx.x;
    int b = blockIdx.x;
    int c = b % HB_CHUNKS;
    int r = (b / HB_CHUNKS) % HB_RANGES;
    int p = b / (HB_CHUNKS * HB_RANGES);
    int r0 = r * HB_BINS;
    int bound = min(HB_BINS, N_NODES - r0);
    const int* basep = pcnt_in + (size_t)c * NROWS_ALL + p * N_NODES + r0;
    for (int i = tid; i < bound; i += 256) curs[i] = basep[i];
    __syncthreads();
    const int4* sp4 = (const int4*)(esrc + (size_t)p * N_EDGES + c * CHUNK_E);
    const int4* dp4 = (const int4*)(edst + (size_t)p * N_EDGES + c * CHUNK_E);
    for (int i = tid * 2; i < CHUNK_E / 4; i += 512) {
        int4 dv0 = dp4[i];
        int4 dv1 = dp4[i + 1];
        int4 sv0 = sp4[i];
        int4 sv1 = sp4[i + 1];
        int l0 = dv0.x - r0; if ((unsigned)l0 < HB_BINS) { int pos = atomicAdd(&curs[l0], 1); col[pos] = (unsigned short)sv0.x; }
        int l1 = dv0.y - r0; if ((unsigned)l1 < HB_BINS) { int pos = atomicAdd(&curs[l1], 1); col[pos] = (unsigned short)sv0.y; }
        int l2 = dv0.z - r0; if ((unsigned)l2 < HB_BINS) { int pos = atomicAdd(&curs[l2], 1); col[pos] = (unsigned short)sv0.z; }
        int l3 = dv0.w - r0; if ((unsigned)l3 < HB_BINS) { int pos = atomicAdd(&curs[l3], 1); col[pos] = (unsigned short)sv0.w; }
        int l4 = dv1.x - r0; if ((unsigned)l4 < HB_BINS) { int pos = atomicAdd(&curs[l4], 1); col[pos] = (unsigned short)sv1.x; }
        int l5 = dv1.y - r0; if ((unsigned)l5 < HB_BINS) { int pos = atomicAdd(&curs[l5], 1); col[pos] = (unsigned short)sv1.y; }
        int l6 = dv1.z - r0; if ((unsigned)l6 < HB_BINS) { int pos = atomicAdd(&curs[l6], 1); col[pos] = (unsigned short)sv1.z; }
        int l7 = dv1.w - r0; if ((unsigned)l7 < HB_BINS) { int pos = atomicAdd(&curs[l7], 1); col[pos] = (unsigned short)sv1.w; }
    }
}

// ---------------- gather: 4 edge-slots x 16 lanes x 8 dims, e-loop unrolled x2 ----------------
__global__ __launch_bounds__(256) void gather_kernel(const int* __restrict__ cursor,
                                                     const int* __restrict__ cnt_in,
                                                     const unsigned short* __restrict__ col,
                                                     const float* __restrict__ sc_out,
                                                     const uint4* __restrict__ hb4,
                                                     uint4* __restrict__ aggb4) {
    int wid = blockIdx.x * 4 + (threadIdx.x >> 6);
    int lane = threadIdx.x & 63;
    int ss = lane >> 4;
    int ln = lane & 15;
    if (wid >= NROWS_ALL) return;
    int p = wid / N_NODES;
    int beg = cursor[wid];
    int end = beg + cnt_in[wid];
    const float* scp = sc_out + p * N_NODES;
    float acc[8] = {};
    int e = beg + ss;
    for (; e + 4 < end; e += 8) {
        int s0 = col[e];
        int s1 = col[e + 4];
        float c0 = scp[s0];
        float c1 = scp[s1];
        uint4 v0 = hb4[s0 * 16 + ln];
        uint4 v1 = hb4[s1 * 16 + ln];
        acc[0] = fmaf(__uint_as_float(v0.x << 16),        c0, acc[0]);
        acc[1] = fmaf(__uint_as_float(v0.x & 0xFFFF0000u), c0, acc[1]);
        acc[2] = fmaf(__uint_as_float(v0.y << 16),        c0, acc[2]);
        acc[3] = fmaf(__uint_as_float(v0.y & 0xFFFF0000u), c0, acc[3]);
        acc[4] = fmaf(__uint_as_float(v0.z << 16),        c0, acc[4]);
        acc[5] = fmaf(__uint_as_float(v0.z & 0xFFFF0000u), c0, acc[5]);
        acc[6] = fmaf(__uint_as_float(v0.w << 16),        c0, acc[6]);
        acc[7] = fmaf(__uint_as_float(v0.w & 0xFFFF0000u), c0, acc[7]);
        acc[0] = fmaf(__uint_as_float(v1.x << 16),        c1, acc[0]);
        acc[1] = fmaf(__uint_as_float(v1.x & 0xFFFF0000u), c1, acc[1]);
        acc[2] = fmaf(__uint_as_float(v1.y << 16),        c1, acc[2]);
        acc[3] = fmaf(__uint_as_float(v1.y & 0xFFFF0000u), c1, acc[3]);
        acc[4] = fmaf(__uint_as_float(v1.z << 16),        c1, acc[4]);
        acc[5] = fmaf(__uint_as_float(v1.z & 0xFFFF0000u), c1, acc[5]);
        acc[6] = fmaf(__uint_as_float(v1.w << 16),        c1, acc[6]);
        acc[7] = fmaf(__uint_as_float(v1.w & 0xFFFF0000u), c1, acc[7]);
    }
    if (e < end) {
        int s0 = col[e];
        float c0 = scp[s0];
        uint4 v0 = hb4[s0 * 16 + ln];
        acc[0] = fmaf(__uint_as_float(v0.x << 16),        c0, acc[0]);
        acc[1] = fmaf(__uint_as_float(v0.x & 0xFFFF0000u), c0, acc[1]);
        acc[2] = fmaf(__uint_as_float(v0.y << 16),        c0, acc[2]);
        acc[3] = fmaf(__uint_as_float(v0.y & 0xFFFF0000u), c0, acc[3]);
        acc[4] = fmaf(__uint_as_float(v0.z << 16),        c0, acc[4]);
        acc[5] = fmaf(__uint_as_float(v0.z & 0xFFFF0000u), c0, acc[5]);
        acc[6] = fmaf(__uint_as_float(v0.w << 16),        c0, acc[6]);
        acc[7] = fmaf(__uint_as_float(v0.w & 0xFFFF0000u), c0, acc[7]);
    }
#pragma unroll
    for (int j = 0; j < 8; ++j) {
        acc[j] += __shfl_xor(acc[j], 16, 64);
        acc[j] += __shfl_xor(acc[j], 32, 64);
    }
    if (ss == 0) {
        uint4 o;
        o.x = f2bf(acc[0]) | ((unsigned)f2bf(acc[1]) << 16);
        o.y = f2bf(acc[2]) | ((unsigned)f2bf(acc[3]) << 16);
        o.z = f2bf(acc[4]) | ((unsigned)f2bf(acc[5]) << 16);
        o.w = f2bf(acc[6]) | ((unsigned)f2bf(acc[7]) << 16);
        int t = wid >> 4, m = wid & 15, q = ln >> 2, qd = ln & 3;
        aggb4[(size_t)t * 256 + q * 64 + qd * 16 + m] = o;
    }
}

// ---------------- score pass: gemm1 -> LDS transpose -> gemm2 -> tanh -> score ----------------
__global__ __launch_bounds__(256, 4) void score_pass(const uint4* __restrict__ aggb4,
                                                     const uint4* __restrict__ wsw,
                                                     const int* __restrict__ cnt_in,
                                                     const float* __restrict__ b_gc,
                                                     const float* __restrict__ b1,
                                                     const float* __restrict__ w2,
                                                     float* __restrict__ scorep) {
    __shared__ float zS[4][16][132];
    int wave = threadIdx.x >> 6, lane = threadIdx.x & 63;
    int m = lane & 15, quad = lane >> 4;
    int t = blockIdx.x * 4 + wave;
    if (t >= NTILES_ALL) return;
    int r0 = t * 16;
    int p = r0 / N_NODES;
    const uint4* At = aggb4 + (size_t)t * 256 + lane;
    bf16x8 a[4];
#pragma unroll
    for (int q = 0; q < 4; ++q) a[q] = *(const bf16x8*)&At[q * 64];
    float s[4];
#pragma unroll
    for (int rg = 0; rg < 4; ++rg)
        s[rg] = rsqrtf(fmaxf((float)cnt_in[r0 + quad * 4 + rg], 1.0f));
    const uint4* Bp = wsw + (size_t)p * 2048 + lane;
    const float* bgc = b_gc + p * DIM;
    float (*zw)[132] = zS[wave];
#pragma unroll
    for (int n0 = 0; n0 < 8; ++n0) {
        f32x4 acc = {0.f, 0.f, 0.f, 0.f};
#pragma unroll
        for (int q = 0; q < 4; ++q) {
            bf16x8 b = *(const bf16x8*)&Bp[(n0 * 4 + q) * 64];
            acc = __builtin_amdgcn_mfma_f32_16x16x32_bf16(a[q], b, acc, 0, 0, 0);
        }
        int colj = n0 * 16 + m;
        float bias = bgc[colj];
#pragma unroll
        for (int rg = 0; rg < 4; ++rg)
            zw[quad * 4 + rg][colj] = acc[rg] * s[rg] + bias;
    }
    bf16x8 sa[4];
#pragma unroll
    for (int q = 0; q < 4; ++q) {
        const float* pr = &zw[m][q * 32 + quad * 8];
        float4 f0 = *(const float4*)pr;
        float4 f1 = *(const float4*)(pr + 4);
        bf16x8 tt;
        tt[0] = f2bf(f0.x); tt[1] = f2bf(f0.y); tt[2] = f2bf(f0.z); tt[3] = f2bf(f0.w);
        tt[4] = f2bf(f1.x); tt[5] = f2bf(f1.y); tt[6] = f2bf(f1.z); tt[7] = f2bf(f1.w);
        sa[q] = tt;
    }
    const uint4* W1 = wsw + (size_t)N_PATHS * 2048 + lane;
    float rsum[4] = {0.f, 0.f, 0.f, 0.f};
#pragma unroll
    for (int n0 = 0; n0 < 8; ++n0) {
        f32x4 acc = {0.f, 0.f, 0.f, 0.f};
#pragma unroll
        for (int q = 0; q < 4; ++q) {
            bf16x8 b = *(const bf16x8*)&W1[(n0 * 4 + q) * 64];
            acc = __builtin_amdgcn_mfma_f32_16x16x32_bf16(sa[q], b, acc, 0, 0, 0);
        }
        int colj = n0 * 16 + m;
        float bj = b1[colj], wj = w2[colj];
#pragma unroll
        for (int rg = 0; rg < 4; ++rg)
            rsum[rg] += tanh_fast(acc[rg] + bj) * wj;
    }
#pragma unroll
    for (int off = 1; off < 64; off <<= 1)
#pragma unroll
        for (int rg = 0; rg < 4; ++rg) rsum[rg] += __shfl_xor(rsum[rg], off, 64);
    if (lane == 0)
        scorep[t] = rsum[0] + rsum[1] + rsum[2] + rsum[3];
}

// ---------------- beta = softmax( path-bucketed mean of scorep ) ----------------
__global__ __launch_bounds__(1024) void beta_kernel(const float* __restrict__ scorep,
                                                    float* __restrict__ beta) {
    __shared__ float red[3][1024];
    int t = threadIdx.x;
    float a0 = 0.f, a1 = 0.f, a2 = 0.f;
    for (int i = t; i < NTILES_ALL; i += 1024) {
        float v = scorep[i];
        int p = (i * 16) / N_NODES;
        if (p == 0) a0 += v; else if (p == 1) a1 += v; else a2 += v;
    }
    red[0][t] = a0; red[1][t] = a1; red[2][t] = a2;
    __syncthreads();
    for (int off = 512; off > 0; off >>= 1) {
        if (t < off) {
            red[0][t] += red[0][t + off];
            red[1][t] += red[1][t + off];
            red[2][t] += red[2][t + off];
        }
        __syncthreads();
    }
    if (t == 0) {
        float a = red[0][0] / (float)N_NODES;
        float b = red[1][0] / (float)N_NODES;
        float c = red[2][0] / (float)N_NODES;
        float mx = fmaxf(a, fmaxf(b, c));
        float e0 = expf(a - mx), e1 = expf(b - mx), e2 = expf(c - mx);
        float sm = e0 + e1 + e2;
        beta[0] = e0 / sm; beta[1] = e1 / sm; beta[2] = e2 / sm;
    }
}

// ---------------- out pass: out = sum_p beta_p * ((agg_p @ W_p)*s + b_p) ----------------
__global__ __launch_bounds__(256, 4) void out_pass(const uint4* __restrict__ aggb4,
                                                   const uint4* __restrict__ wsw,
                                                   const int* __restrict__ cnt_in,
                                                   const float* __restrict__ b_gc,
                                                   const float* __restrict__ beta,
                                                   float* __restrict__ out) {
    __shared__ float zS[4][16][132];
    int wave = threadIdx.x >> 6, lane = threadIdx.x & 63;
    int m = lane & 15, quad = lane >> 4;
    int t = blockIdx.x * 4 + wave;
    if (t >= NTILES_N) return;
    int r0 = t * 16;
    float of[8][4] = {};
#pragma unroll
    for (int p = 0; p < N_PATHS; ++p) {
        const uint4* At = aggb4 + (size_t)(p * NTILES_N + t) * 256 + lane;
        bf16x8 a[4];
#pragma unroll
        for (int q = 0; q < 4; ++q) a[q] = *(const bf16x8*)&At[q * 64];
        float s[4];
#pragma unroll
        for (int rg = 0; rg < 4; ++rg)
            s[rg] = rsqrtf(fmaxf((float)cnt_in[p * N_NODES + r0 + quad * 4 + rg], 1.0f));
        float bp = beta[p];
        const uint4* Bp = wsw + (size_t)p * 2048 + lane;
        const float* bgc = b_gc + p * DIM;
#pragma unroll
        for (int n0 = 0; n0 < 8; ++n0) {
            f32x4 acc = {0.f, 0.f, 0.f, 0.f};
#pragma unroll
            for (int q = 0; q < 4; ++q) {
                bf16x8 b = *(const bf16x8*)&Bp[(n0 * 4 + q) * 64];
                acc = __builtin_amdgcn_mfma_f32_16x16x32_bf16(a[q], b, acc, 0, 0, 0);
            }
            float bias = bgc[n0 * 16 + m];
#pragma unroll
            for (int rg = 0; rg < 4; ++rg)
                of[n0][rg] = fmaf(bp, acc[rg] * s[rg] + bias, of[n0][rg]);
        }
    }
    float (*zw)[132] = zS[wave];
#pragma unroll
    for (int n0 = 0; n0 < 8; ++n0)
#pragma unroll
        for (int rg = 0; rg < 4; ++rg)
            zw[quad * 4 + rg][n0 * 16 + m] = of[n0][rg];
#pragma unroll
    for (int i = 0; i < 8; ++i) {
        int fi = i * 64 + lane;
        int row = fi >> 5, c4 = fi & 31;
        float4 v = *(const float4*)&zw[row][c4 * 4];
        *(float4*)(out + (size_t)(r0 + row) * DIM + c4 * 4) = v;
    }
}

extern "C" void kernel_launch(void* const* d_in, const int* in_sizes, int n_in,
                              void* d_out, int out_size, void* d_ws, size_t ws_size,
                              hipStream_t stream) {
    const float* h    = (const float*)d_in[0];
    const float* W_gc = (const float*)d_in[1];
    const float* b_gc = (const float*)d_in[2];
    const float* w1   = (const float*)d_in[3];
    const float* b1   = (const float*)d_in[4];
    const float* w2   = (const float*)d_in[5];
    const int* esrc   = (const int*)d_in[6];
    const int* edst   = (const int*)d_in[7];
    float* out        = (float*)d_out;

    // workspace layout (4-byte word offsets)
    int*   cnt_out = (int*)d_ws;                                // 150000
    int*   cnt_in  = cnt_out + NROWS_ALL;                       // 150000
    float* beta    = (float*)d_ws + 300004;                     // 4 (+pad)
    int*   partial = (int*)d_ws + 300032;                       // 256
    float* sc_out  = (float*)d_ws + 300288;                     // 150000 (reused as scorep)
    float* scorep  = (float*)d_ws + 300288;                     //   after gather completes
    uint4* wsw     = (uint4*)((int*)d_ws + 450288);             // 32768 words
    unsigned int* aggb = (unsigned int*)((int*)d_ws + 483056);  // 9.6M words
    int*   cursor  = (int*)d_ws + 10083056;                     // 150000
    unsigned short* col = (unsigned short*)((int*)d_ws + 10233056);  // 900000 words
    unsigned int*   hb  = (unsigned int*)((int*)d_ws + 11133056);    // 3.2M words
    int*   pcnt_out = (int*)d_ws + 14333056;                    // 24*150000 = 3.6M words
    int*   pcnt_in  = (int*)d_ws + 17933056;                    // 3.6M words (ends 21.53M < 29.28M)

    conv_h<<<(N_NODES * DIM / 8 + 255) / 256, 256, 0, stream>>>(h, hb);
    conv_w<<<((N_PATHS + 1) * 2048 + 255) / 256, 256, 0, stream>>>(W_gc, w1, wsw);

    hist_kernel<<<2 * N_PATHS * HB_RANGES * HB_CHUNKS, 256, 0, stream>>>(
        esrc, edst, pcnt_out, pcnt_in);

    scan_pass1<<<SCAN_BLOCKS, 256, 0, stream>>>(
        pcnt_out, pcnt_in, cnt_out, cnt_in, sc_out, partial);
    scan_pass2<<<1, 256, 0, stream>>>(partial);
    scan_pass3<<<SCAN_BLOCKS, 256, 0, stream>>>(cnt_in, partial, cursor, pcnt_in);

    fill2_kernel<<<N_PATHS * HB_RANGES * HB_CHUNKS, 256, 0, stream>>>(
        esrc, edst, pcnt_in, col);

    gather_kernel<<<(NROWS_ALL + 3) / 4, 256, 0, stream>>>(
        cursor, cnt_in, col, sc_out, (const uint4*)hb, (uint4*)aggb);

    score_pass<<<(NTILES_ALL + 3) / 4, 256, 0, stream>>>(
        (const uint4*)aggb, wsw, cnt_in, b_gc, b1, w2, scorep);

    beta_kernel<<<1, 1024, 0, stream>>>(scorep, beta);

    out_pass<<<(NTILES_N + 3) / 4, 256, 0, stream>>>(
        (const uint4*)aggb, wsw, cnt_in, b_gc, beta, out);
}